// Round 14
// baseline (883.561 us; speedup 1.0000x reference)
//
#include <hip/hip_runtime.h>
#include <hip/hip_bf16.h>

#define B_  16
#define C_  256
#define N_  1024
#define H_  4

typedef unsigned short u16;
typedef __attribute__((ext_vector_type(8))) short bf16x8;
typedef __attribute__((ext_vector_type(4))) float f32x4;

#if __has_builtin(__builtin_amdgcn_exp2f)
#define EXP2(x) __builtin_amdgcn_exp2f(x)
#else
#define EXP2(x) __builtin_exp2f(x)
#endif

__device__ __forceinline__ u16 f2bf(float f) {
    union { float f; unsigned u; } v; v.f = f;
    unsigned r = v.u + 0x7FFFu + ((v.u >> 16) & 1u);
    return (u16)(r >> 16);
}
__device__ __forceinline__ float bf2f(u16 h) {
    union { unsigned u; float f; } v; v.u = ((unsigned)h) << 16;
    return v.f;
}
__device__ __forceinline__ unsigned pack2bf(float a, float b) {
    __hip_bfloat162 h = __float22bfloat162_rn(make_float2(a, b));
    union { __hip_bfloat162 h2; unsigned u; } cv; cv.h2 = h;
    return cv.u;
}
// async global->LDS, 16B per lane; lds base must be wave-uniform
__device__ __forceinline__ void gl_lds16(const u16* g, u16* l) {
    __builtin_amdgcn_global_load_lds(
        (const __attribute__((address_space(1))) void*)g,
        (__attribute__((address_space(3))) void*)l, 16, 0, 0);
}

// ---- weights f32->bf16 arena (wq|wkv|wlq|wproj|wlkv) + dw weight transpose ----
__global__ __launch_bounds__(256) void k_f2bf5(const float* __restrict__ a0,
                                               const float* __restrict__ a1,
                                               const float* __restrict__ a2,
                                               const float* __restrict__ a3,
                                               const float* __restrict__ a4,
                                               u16* __restrict__ dst,
                                               const float* __restrict__ dw_w,
                                               float* __restrict__ wT) {
    if (blockIdx.x == 448) {  // dw weights [256][9] -> [9][256]
        int i = threadIdx.x;
#pragma unroll
        for (int tap = 0; tap < 9; tap++)
            wT[tap * 256 + i] = dw_w[i * 9 + tap];
        return;
    }
    int i = blockIdx.x * 256 + threadIdx.x;  // float4 index, total 114688
    const float* s; int off;
    if (i < 16384)      { s = a0; off = 0; }
    else if (i < 49152) { s = a1; off = 16384; }
    else if (i < 65536) { s = a2; off = 49152; }
    else if (i < 81920) { s = a3; off = 65536; }
    else                { s = a4; off = 81920; }
    float4 v = reinterpret_cast<const float4*>(s)[i - off];
    ushort4 o;
    o.x = f2bf(v.x); o.y = f2bf(v.y); o.z = f2bf(v.z); o.w = f2bf(v.w);
    reinterpret_cast<ushort4*>(dst)[i] = o;
}

// ---------------- x[b][c][n] f32 -> xf[b][n][c] bf16 ----------------
__global__ __launch_bounds__(256) void k_transpose_x(const float* __restrict__ x,
                                                     u16* __restrict__ xf) {
    __shared__ u16 tile[32][33];
    int b = blockIdx.z;
    int n0 = blockIdx.x * 32, c0 = blockIdx.y * 32;
    int tx = threadIdx.x, ty = threadIdx.y;  // 32 x 8
#pragma unroll
    for (int i = 0; i < 4; i++)
        tile[ty + i * 8][tx] =
            f2bf(x[((size_t)(b * C_ + c0 + ty + i * 8)) * N_ + n0 + tx]);
    __syncthreads();
#pragma unroll
    for (int i = 0; i < 4; i++)
        xf[((size_t)(b * N_ + n0 + ty + i * 8)) * C_ + c0 + tx] = tile[tx][ty + i * 8];
}

// ---- pack K into MFMA-fragment chunk order (rperm baked in); coalesced stores ----
__global__ __launch_bounds__(256) void k_packK(const u16* __restrict__ Ksrc, int kstr,
                                               u16* __restrict__ Kpk) {
    int tid = blockIdx.x * 256 + threadIdx.x;  // 524288 total
    int lane = tid & 63;
    int chunk = tid >> 6;                      // 8192 chunks
    int c = chunk & 7;
    int kb = (chunk >> 3) & 15;
    int bh = chunk >> 7;                       // b*4+h
    int h = bh & 3, b = bh >> 2;
    int nt = c >> 1, w2 = c & 1;
    int l16 = lane & 15, g = lane >> 4;
    int rn = kb * 64 + (nt >> 1) * 32 + (nt & 1) * 4 + (((l16 & 12) << 1) | (l16 & 3));
    const u16* src = Ksrc + (size_t)(b * N_ + rn) * kstr + h * 64 + w2 * 32 + g * 8;
    *reinterpret_cast<bf16x8*>(&Kpk[(size_t)chunk * 512 + lane * 8]) =
        *reinterpret_cast<const bf16x8*>(src);
}

// ---- pack V^T into MFMA-fragment chunk order ----
__global__ __launch_bounds__(256) void k_packV(const u16* __restrict__ src, int stride,
                                               u16* __restrict__ Vpk) {
    __shared__ u16 tile[32][33];
    int b = blockIdx.z;
    int n0 = blockIdx.x * 32, vc0 = blockIdx.y * 32;  // vc0 in [0,256)
    int h = vc0 >> 6, dl = vc0 & 63;
    int bh = b * 4 + h;
    int kb = n0 >> 6, kc = (n0 >> 5) & 1;
    int tx = threadIdx.x, ty = threadIdx.y;
#pragma unroll
    for (int i = 0; i < 4; i++)
        tile[ty + i * 8][tx] =
            src[(size_t)(b * N_ + n0 + ty + i * 8) * stride + vc0 + tx];
    __syncthreads();
    int g = (tx >> 3) & 3, j = tx & 7;
#pragma unroll
    for (int i = 0; i < 4; i++) {
        int cl = ty + i * 8;            // d-local 0..31
        int d = dl + cl;
        int dt = d >> 4;
        int lane = (d & 15) + 16 * g;
        size_t addr = ((size_t)(bh * 16 + kb) * 8 + kc * 4 + dt) * 512 + lane * 8 + j;
        Vpk[addr] = tile[tx][cl];
    }
}

// -------- MFMA GEMM (m97-style): linear LDS + global_load_lds width-16 --------
// A rows stride astr, C rows stride ldc. Tile 128x128, BK=32, 4 waves.
__global__ __launch_bounds__(256) void k_gemm_bf16(const u16* __restrict__ A, int astr,
                                                   const u16* __restrict__ W,
                                                   const float* __restrict__ bias,
                                                   u16* __restrict__ C,
                                                   int Nout, int ldc) {
    __shared__ u16 As[128 * 32];
    __shared__ u16 Bs[128 * 32];
    int m0 = blockIdx.y * 128, n0 = blockIdx.x * 128;
    int t = threadIdx.x;
    int wid = t >> 6, lane = t & 63;
    int l16 = lane & 15, g = lane >> 4;
    int wm = (wid >> 1) * 64, wn = (wid & 1) * 64;
    int srow0 = (lane >> 2);
    int scol = (lane & 3) * 8;
    f32x4 zz = {0.f, 0.f, 0.f, 0.f};
    f32x4 acc[4][4];
#pragma unroll
    for (int i = 0; i < 4; i++)
#pragma unroll
        for (int j = 0; j < 4; j++) acc[i][j] = zz;
    for (int k0 = 0; k0 < 256; k0 += 32) {
        __syncthreads();
#pragma unroll
        for (int i = 0; i < 2; i++) {
            int rr = (wid * 2 + i) * 16;
            gl_lds16(A + (size_t)(m0 + rr + srow0) * astr + k0 + scol, &As[rr * 32]);
            gl_lds16(W + (size_t)(n0 + rr + srow0) * 256 + k0 + scol, &Bs[rr * 32]);
        }
        __syncthreads();
        bf16x8 af[4], bfr[4];
#pragma unroll
        for (int mt = 0; mt < 4; mt++)
            af[mt] = *reinterpret_cast<const bf16x8*>(&As[(wm + mt * 16 + l16) * 32 + g * 8]);
#pragma unroll
        for (int nt = 0; nt < 4; nt++)
            bfr[nt] = *reinterpret_cast<const bf16x8*>(&Bs[(wn + nt * 16 + l16) * 32 + g * 8]);
#pragma unroll
        for (int mt = 0; mt < 4; mt++)
#pragma unroll
            for (int nt = 0; nt < 4; nt++)
                acc[mt][nt] = __builtin_amdgcn_mfma_f32_16x16x32_bf16(
                    af[mt], bfr[nt], acc[mt][nt], 0, 0, 0);
    }
    float bval[4];
#pragma unroll
    for (int nt = 0; nt < 4; nt++) {
        int n = n0 + wn + nt * 16 + l16;
        bval[nt] = bias ? bias[n] : 0.0f;
    }
#pragma unroll
    for (int mt = 0; mt < 4; mt++)
#pragma unroll
        for (int r = 0; r < 4; r++) {
            int m = m0 + wm + mt * 16 + g * 4 + r;
#pragma unroll
            for (int nt = 0; nt < 4; nt++) {
                int n = n0 + wn + nt * 16 + l16;
                C[(size_t)m * ldc + n] = f2bf(acc[mt][nt][r] + bval[nt]);
            }
        }
}

// ------- depthwise 3x3 conv + bias + residual, vectorized (short8/lane) -------
__global__ __launch_bounds__(256) void k_dwconv_add(const u16* __restrict__ yp,
                                                    const float* __restrict__ wT,
                                                    const float* __restrict__ dw_b,
                                                    u16* __restrict__ out) {
    int b = blockIdx.y;
    int px = blockIdx.x * 8 + (threadIdx.x >> 5);
    int cc0 = (threadIdx.x & 31) * 8;
    int yy = px >> 5, xx = px & 31;
    const u16* ypb = yp + (size_t)b * N_ * C_;
    float acc[8];
    {
        float4 b0 = *reinterpret_cast<const float4*>(&dw_b[cc0]);
        float4 b1 = *reinterpret_cast<const float4*>(&dw_b[cc0 + 4]);
        acc[0] = b0.x; acc[1] = b0.y; acc[2] = b0.z; acc[3] = b0.w;
        acc[4] = b1.x; acc[5] = b1.y; acc[6] = b1.z; acc[7] = b1.w;
    }
#pragma unroll
    for (int dy = 0; dy < 3; dy++) {
        int y2 = yy + dy - 1;
        if (y2 < 0 || y2 >= 32) continue;
#pragma unroll
        for (int dx = 0; dx < 3; dx++) {
            int x2 = xx + dx - 1;
            if (x2 < 0 || x2 >= 32) continue;
            int tap = dy * 3 + dx;
            bf16x8 v = *reinterpret_cast<const bf16x8*>(
                &ypb[(size_t)(y2 * 32 + x2) * C_ + cc0]);
            float4 w0 = *reinterpret_cast<const float4*>(&wT[tap * 256 + cc0]);
            float4 w1 = *reinterpret_cast<const float4*>(&wT[tap * 256 + cc0 + 4]);
            acc[0] += bf2f((u16)v[0]) * w0.x;
            acc[1] += bf2f((u16)v[1]) * w0.y;
            acc[2] += bf2f((u16)v[2]) * w0.z;
            acc[3] += bf2f((u16)v[3]) * w0.w;
            acc[4] += bf2f((u16)v[4]) * w1.x;
            acc[5] += bf2f((u16)v[5]) * w1.y;
            acc[6] += bf2f((u16)v[6]) * w1.z;
            acc[7] += bf2f((u16)v[7]) * w1.w;
        }
    }
    bf16x8 ctr = *reinterpret_cast<const bf16x8*>(&ypb[(size_t)px * C_ + cc0]);
    bf16x8 o;
#pragma unroll
    for (int j = 0; j < 8; j++)
        o[j] = (short)f2bf(acc[j] + bf2f((u16)ctr[j]));
    *reinterpret_cast<bf16x8*>(&out[((size_t)b * N_ + px) * C_ + cc0]) = o;
}

// -------- MFMA flash attention: all-register P, packed K/V, 4-way kv-split ----
// Block = 4 waves over the SAME 32 q-rows; wave wv covers kv tiles
// [wv*4, wv*4+4). No-max softmax partials combine linearly via a 2-stage LDS
// tree reduce (1,3 -> 0,2 then 2 -> 0). Grid 2048 = 8 blocks/CU (32 waves/CU).
template <int STAGE>
__global__ __launch_bounds__(256, 6) void k_attn_mfma(const u16* __restrict__ Q, int qstr,
                                                      const u16* __restrict__ Kpk,
                                                      const u16* __restrict__ Vpk,
                                                      void* __restrict__ outp, int ostr) {
    __shared__ union { float Cmb[2][64][33]; float Os[32][68]; } sm;
    __shared__ float Clsum[2][64][2];
    int cid = blockIdx.x;
    int xcd = cid & 7, slot = cid >> 3;  // slot in [0,256)
    int bh = xcd * 8 + (slot & 7);       // 64 (b,h) panels, 8 per XCD
    int qc = slot >> 3;                  // q-chunk 0..31 (32 rows each)
    int h = bh & 3, b = bh >> 2;
    int t = threadIdx.x;
    int wv = t >> 6, lane = t & 63;      // wv = kv quarter
    int l16 = lane & 15, g = lane >> 4, g8 = g * 8;

    const float SCL = 0.18033688011112042f;  // 0.125*log2(e)
    const u16* Qb =
        Q + ((size_t)(b * N_ + qc * 32 + l16)) * qstr + h * 64 + g8;
    bf16x8 qf[2][2];
#pragma unroll
    for (int qg = 0; qg < 2; qg++)
#pragma unroll
        for (int w2 = 0; w2 < 2; w2++) {
            qf[qg][w2] = *reinterpret_cast<const bf16x8*>(Qb + qg * 16 * qstr + w2 * 32);
#pragma unroll
            for (int j = 0; j < 8; j++)
                qf[qg][w2][j] = (short)f2bf(bf2f((u16)qf[qg][w2][j]) * SCL);
        }

    const u16* Kp = Kpk + (size_t)bh * 65536 + lane * 8;
    const u16* Vp = Vpk + (size_t)bh * 65536 + lane * 8;

    int kb0 = wv * 4, kb1 = kb0 + 4;
    bf16x8 kf[4][2];
#pragma unroll
    for (int nt = 0; nt < 4; nt++)
#pragma unroll
        for (int w2 = 0; w2 < 2; w2++)
            kf[nt][w2] = *reinterpret_cast<const bf16x8*>(
                Kp + (size_t)(kb0 * 8 + nt * 2 + w2) * 512);

    f32x4 zz = {0.f, 0.f, 0.f, 0.f};
    f32x4 accO[4][2];
#pragma unroll
    for (int dt = 0; dt < 4; dt++)
#pragma unroll
        for (int qg = 0; qg < 2; qg++) accO[dt][qg] = zz;
    float lsum[2] = {0.f, 0.f};
    int pwv[2][8];

    for (int kb = kb0; kb < kb1; kb++) {
        bf16x8 vf[2][4];
#pragma unroll
        for (int kc = 0; kc < 2; kc++)
#pragma unroll
            for (int dt = 0; dt < 4; dt++)
                vf[kc][dt] = *reinterpret_cast<const bf16x8*>(
                    Vp + (size_t)(kb * 8 + kc * 4 + dt) * 512);
#pragma unroll
        for (int qg = 0; qg < 2; qg++) {
            f32x4 st[4];
#pragma unroll
            for (int nt = 0; nt < 4; nt++) st[nt] = zz;
#pragma unroll
            for (int nt = 0; nt < 4; nt++) {
                st[nt] = __builtin_amdgcn_mfma_f32_16x16x32_bf16(kf[nt][0], qf[qg][0],
                                                                 st[nt], 0, 0, 0);
                st[nt] = __builtin_amdgcn_mfma_f32_16x16x32_bf16(kf[nt][1], qf[qg][1],
                                                                 st[nt], 0, 0, 0);
            }
#pragma unroll
            for (int nt = 0; nt < 4; nt++) {
                float p0 = EXP2(st[nt][0]);
                float p1 = EXP2(st[nt][1]);
                float p2 = EXP2(st[nt][2]);
                float p3 = EXP2(st[nt][3]);
                lsum[qg] += (p0 + p1) + (p2 + p3);
                pwv[qg][nt * 2 + 0] = (int)pack2bf(p0, p1);
                pwv[qg][nt * 2 + 1] = (int)pack2bf(p2, p3);
            }
        }
        {
            int nkb = (kb < kb1 - 1) ? kb + 1 : kb;
#pragma unroll
            for (int nt = 0; nt < 4; nt++)
#pragma unroll
                for (int w2 = 0; w2 < 2; w2++)
                    kf[nt][w2] = *reinterpret_cast<const bf16x8*>(
                        Kp + (size_t)(nkb * 8 + nt * 2 + w2) * 512);
        }
#pragma unroll
        for (int qg = 0; qg < 2; qg++)
#pragma unroll
            for (int kc = 0; kc < 2; kc++) {
                union { int i[4]; bf16x8 v; } u;
                u.i[0] = pwv[qg][4 * kc + 0];
                u.i[1] = pwv[qg][4 * kc + 1];
                u.i[2] = pwv[qg][4 * kc + 2];
                u.i[3] = pwv[qg][4 * kc + 3];
#pragma unroll
                for (int dt = 0; dt < 4; dt++)
                    accO[dt][qg] = __builtin_amdgcn_mfma_f32_16x16x32_bf16(
                        vf[kc][dt], u.v, accO[dt][qg], 0, 0, 0);
            }
    }

    // ---- 2-stage tree reduce across kv quarters (linear partials) ----
    // stage A: waves 1,3 publish; waves 0,2 add
    if (wv & 1) {
#pragma unroll
        for (int dt = 0; dt < 4; dt++)
#pragma unroll
            for (int qg = 0; qg < 2; qg++)
#pragma unroll
                for (int r = 0; r < 4; r++)
                    sm.Cmb[wv >> 1][lane][(dt * 2 + qg) * 4 + r] = accO[dt][qg][r];
        Clsum[wv >> 1][lane][0] = lsum[0];
        Clsum[wv >> 1][lane][1] = lsum[1];
    }
    __syncthreads();
    if (!(wv & 1)) {
#pragma unroll
        for (int dt = 0; dt < 4; dt++)
#pragma unroll
            for (int qg = 0; qg < 2; qg++)
#pragma unroll
                for (int r = 0; r < 4; r++)
                    accO[dt][qg][r] += sm.Cmb[wv >> 1][lane][(dt * 2 + qg) * 4 + r];
        lsum[0] += Clsum[wv >> 1][lane][0];
        lsum[1] += Clsum[wv >> 1][lane][1];
    }
    __syncthreads();
    // stage B: wave 2 publishes; wave 0 adds
    if (wv == 2) {
#pragma unroll
        for (int dt = 0; dt < 4; dt++)
#pragma unroll
            for (int qg = 0; qg < 2; qg++)
#pragma unroll
                for (int r = 0; r < 4; r++)
                    sm.Cmb[0][lane][(dt * 2 + qg) * 4 + r] = accO[dt][qg][r];
        Clsum[0][lane][0] = lsum[0];
        Clsum[0][lane][1] = lsum[1];
    }
    __syncthreads();
    if (wv == 0) {
#pragma unroll
        for (int dt = 0; dt < 4; dt++)
#pragma unroll
            for (int qg = 0; qg < 2; qg++)
#pragma unroll
                for (int r = 0; r < 4; r++)
                    accO[dt][qg][r] += sm.Cmb[0][lane][(dt * 2 + qg) * 4 + r];
        lsum[0] += Clsum[0][lane][0];
        lsum[1] += Clsum[0][lane][1];
        float inv[2];
#pragma unroll
        for (int qg = 0; qg < 2; qg++) {
            float l = lsum[qg];
            l += __shfl_xor(l, 16);
            l += __shfl_xor(l, 32);
            inv[qg] = 1.0f / l;
        }
        if constexpr (STAGE == 0) {
            u16* O = (u16*)outp;
            size_t rowb = (size_t)(b * N_ + qc * 32 + l16);
#pragma unroll
            for (int qg = 0; qg < 2; qg++)
#pragma unroll
                for (int dt = 0; dt < 4; dt++) {
                    ushort4 o;
                    o.x = f2bf(accO[dt][qg][0] * inv[qg]);
                    o.y = f2bf(accO[dt][qg][1] * inv[qg]);
                    o.z = f2bf(accO[dt][qg][2] * inv[qg]);
                    o.w = f2bf(accO[dt][qg][3] * inv[qg]);
                    *reinterpret_cast<ushort4*>(
                        &O[(rowb + qg * 16) * ostr + h * 64 + dt * 16 + g * 4]) = o;
                }
        } else {
            // publish normalized O rows to LDS for the all-thread scatter
            __builtin_amdgcn_s_barrier();  // wait: others done reading Cmb
#pragma unroll
            for (int qg = 0; qg < 2; qg++)
#pragma unroll
                for (int dt = 0; dt < 4; dt++)
#pragma unroll
                    for (int r = 0; r < 4; r++)
                        sm.Os[qg * 16 + l16][dt * 16 + g * 4 + r] = accO[dt][qg][r] * inv[qg];
        }
    } else if constexpr (STAGE == 1) {
        __builtin_amdgcn_s_barrier();  // match wave-0 barrier
    }
    if constexpr (STAGE == 1) {
        __syncthreads();
        // batch-mixing scatter: n = qc*32+row; bo=(n&1)*8+h*2+(b>>3),
        // co=((n>>1)&3)*64+d, no=(b&7)*128+(n>>3); row = j*8+(q2*2+tl), j=0..3
        float* out = (float*)outp;
#pragma unroll
        for (int e = 0; e < 2; e++) {
            int seg = t + e * 256;          // 512 segs = 64 d x 8 (tl,q2)
            int d = seg & 63, tb = seg >> 6;
            int tl = tb & 1, q2 = (tb >> 1) & 3;
            int bo = tl * 8 + h * 2 + (b >> 3);
            int co = q2 * 64 + d;
            size_t base = (size_t)bo * (C_ * N_) + (size_t)co * N_ + (b & 7) * 128 + qc * 4;
            float4 v;
            v.x = sm.Os[0 * 8 + q2 * 2 + tl][d];
            v.y = sm.Os[1 * 8 + q2 * 2 + tl][d];
            v.z = sm.Os[2 * 8 + q2 * 2 + tl][d];
            v.w = sm.Os[3 * 8 + q2 * 2 + tl][d];
            *reinterpret_cast<float4*>(&out[base]) = v;
        }
    }
}

extern "C" void kernel_launch(void* const* d_in, const int* in_sizes, int n_in,
                              void* d_out, int out_size, void* d_ws, size_t ws_size,
                              hipStream_t stream) {
    const float* x      = (const float*)d_in[0];
    const float* q_w    = (const float*)d_in[1];
    const float* kv_w   = (const float*)d_in[2];
    const float* proj_w = (const float*)d_in[3];
    const float* proj_b = (const float*)d_in[4];
    const float* lq_w   = (const float*)d_in[5];
    const float* lq_b   = (const float*)d_in[6];
    const float* lkv_w  = (const float*)d_in[7];
    const float* lkv_b  = (const float*)d_in[8];
    // d_in[9] = rel_bias: constant along softmax axis -> exact no-op
    const float* dw_w   = (const float*)d_in[10];
    const float* dw_b   = (const float*)d_in[11];

    const size_t SZ = (size_t)B_ * N_ * C_;  // 4M elems
    u16* ws = (u16*)d_ws;
    u16* xf    = ws;              // [0,SZ): xf, later s2in
    u16* qkv   = ws + SZ;         // [SZ,4SZ): ldc=768: q/q2 | K | V columns
    u16* Kpk   = ws + 4 * SZ;     // [4SZ,5SZ): packed K, also ypb between stages
    u16* Vpk   = ws + 5 * SZ;     // [5SZ,6SZ): packed V
    u16* arena = ws + 6 * SZ;     // weights: wq|wkv|wlq|wproj|wlkv
    u16* wfused = arena;          // wq|wkv stacked: [768][256]
    u16* wlq    = arena + 196608;
    u16* wproj  = arena + 262144;
    u16* wlkv   = arena + 327680;
    float* wT   = (float*)(arena + 458752);  // [9][256] f32 transposed dw weights
    u16* yb     = qkv + 256;      // attn1 out in dead K columns (stride 768)
    u16* ypb    = Kpk;            // proj out in dead packed-K slot
    u16* s2in   = xf;             // conv+res out in dead xf slot

    k_f2bf5<<<449, 256, 0, stream>>>(q_w, kv_w, lq_w, proj_w, lkv_w, arena, dw_w, wT);
    k_transpose_x<<<dim3(32, 8, B_), dim3(32, 8), 0, stream>>>(x, xf);
    // fused q|kv projections (no bias on either)
    k_gemm_bf16<<<dim3(6, 128), 256, 0, stream>>>(xf, 256, wfused, nullptr, qkv, 768, 768);
    k_packK<<<2048, 256, 0, stream>>>(qkv + 256, 768, Kpk);
    k_packV<<<dim3(32, 8, B_), dim3(32, 8), 0, stream>>>(qkv + 512, 768, Vpk);
    k_attn_mfma<0><<<2048, 256, 0, stream>>>(qkv, 768, Kpk, Vpk, yb, 768);
    // q2 projection into the now-dead q columns
    k_gemm_bf16<<<dim3(2, 128), 256, 0, stream>>>(xf, 256, wlq, lq_b, qkv, 256, 768);
    k_gemm_bf16<<<dim3(2, 128), 256, 0, stream>>>(yb, 768, wproj, proj_b, ypb, 256, 256);
    k_dwconv_add<<<dim3(128, B_), 256, 0, stream>>>(ypb, wT, dw_b, s2in);
    k_gemm_bf16<<<dim3(4, 128), 256, 0, stream>>>(s2in, 256, wlkv, lkv_b, qkv + 256, 512, 768);
    k_packK<<<2048, 256, 0, stream>>>(qkv + 256, 768, Kpk);
    k_packV<<<dim3(32, 8, B_), dim3(32, 8), 0, stream>>>(qkv + 512, 768, Vpk);
    k_attn_mfma<1><<<2048, 256, 0, stream>>>(qkv, 768, Kpk, Vpk, d_out, 0);
}

// Round 15
// 402.932 us; speedup vs baseline: 2.1928x; 2.1928x over previous
//
#include <hip/hip_runtime.h>
#include <hip/hip_bf16.h>

#define B_  16
#define C_  256
#define N_  1024
#define H_  4

typedef unsigned short u16;
typedef __attribute__((ext_vector_type(8))) short bf16x8;
typedef __attribute__((ext_vector_type(4))) float f32x4;

#if __has_builtin(__builtin_amdgcn_exp2f)
#define EXP2(x) __builtin_amdgcn_exp2f(x)
#else
#define EXP2(x) __builtin_exp2f(x)
#endif

__device__ __forceinline__ u16 f2bf(float f) {
    union { float f; unsigned u; } v; v.f = f;
    unsigned r = v.u + 0x7FFFu + ((v.u >> 16) & 1u);
    return (u16)(r >> 16);
}
__device__ __forceinline__ float bf2f(u16 h) {
    union { unsigned u; float f; } v; v.u = ((unsigned)h) << 16;
    return v.f;
}
__device__ __forceinline__ unsigned pack2bf(float a, float b) {
    __hip_bfloat162 h = __float22bfloat162_rn(make_float2(a, b));
    union { __hip_bfloat162 h2; unsigned u; } cv; cv.h2 = h;
    return cv.u;
}
// async global->LDS, 16B per lane; lds base must be wave-uniform
__device__ __forceinline__ void gl_lds16(const u16* g, u16* l) {
    __builtin_amdgcn_global_load_lds(
        (const __attribute__((address_space(1))) void*)g,
        (__attribute__((address_space(3))) void*)l, 16, 0, 0);
}

// ---- weights f32->bf16 arena (wq|wkv|wlq|wproj|wlkv) + dw weight transpose ----
__global__ __launch_bounds__(256) void k_f2bf5(const float* __restrict__ a0,
                                               const float* __restrict__ a1,
                                               const float* __restrict__ a2,
                                               const float* __restrict__ a3,
                                               const float* __restrict__ a4,
                                               u16* __restrict__ dst,
                                               const float* __restrict__ dw_w,
                                               float* __restrict__ wT) {
    if (blockIdx.x == 448) {  // dw weights [256][9] -> [9][256]
        int i = threadIdx.x;
#pragma unroll
        for (int tap = 0; tap < 9; tap++)
            wT[tap * 256 + i] = dw_w[i * 9 + tap];
        return;
    }
    int i = blockIdx.x * 256 + threadIdx.x;  // float4 index, total 114688
    const float* s; int off;
    if (i < 16384)      { s = a0; off = 0; }
    else if (i < 49152) { s = a1; off = 16384; }
    else if (i < 65536) { s = a2; off = 49152; }
    else if (i < 81920) { s = a3; off = 65536; }
    else                { s = a4; off = 81920; }
    float4 v = reinterpret_cast<const float4*>(s)[i - off];
    ushort4 o;
    o.x = f2bf(v.x); o.y = f2bf(v.y); o.z = f2bf(v.z); o.w = f2bf(v.w);
    reinterpret_cast<ushort4*>(dst)[i] = o;
}

// ---------------- x[b][c][n] f32 -> xf[b][n][c] bf16 ----------------
__global__ __launch_bounds__(256) void k_transpose_x(const float* __restrict__ x,
                                                     u16* __restrict__ xf) {
    __shared__ u16 tile[32][33];
    int b = blockIdx.z;
    int n0 = blockIdx.x * 32, c0 = blockIdx.y * 32;
    int tx = threadIdx.x, ty = threadIdx.y;  // 32 x 8
#pragma unroll
    for (int i = 0; i < 4; i++)
        tile[ty + i * 8][tx] =
            f2bf(x[((size_t)(b * C_ + c0 + ty + i * 8)) * N_ + n0 + tx]);
    __syncthreads();
#pragma unroll
    for (int i = 0; i < 4; i++)
        xf[((size_t)(b * N_ + n0 + ty + i * 8)) * C_ + c0 + tx] = tile[tx][ty + i * 8];
}

// ---- pack K into MFMA-fragment chunk order (rperm baked in); coalesced stores ----
__global__ __launch_bounds__(256) void k_packK(const u16* __restrict__ Ksrc, int kstr,
                                               u16* __restrict__ Kpk) {
    int tid = blockIdx.x * 256 + threadIdx.x;  // 524288 total
    int lane = tid & 63;
    int chunk = tid >> 6;                      // 8192 chunks
    int c = chunk & 7;
    int kb = (chunk >> 3) & 15;
    int bh = chunk >> 7;                       // b*4+h
    int h = bh & 3, b = bh >> 2;
    int nt = c >> 1, w2 = c & 1;
    int l16 = lane & 15, g = lane >> 4;
    int rn = kb * 64 + (nt >> 1) * 32 + (nt & 1) * 4 + (((l16 & 12) << 1) | (l16 & 3));
    const u16* src = Ksrc + (size_t)(b * N_ + rn) * kstr + h * 64 + w2 * 32 + g * 8;
    *reinterpret_cast<bf16x8*>(&Kpk[(size_t)chunk * 512 + lane * 8]) =
        *reinterpret_cast<const bf16x8*>(src);
}

// ---- pack V^T into MFMA-fragment chunk order ----
__global__ __launch_bounds__(256) void k_packV(const u16* __restrict__ src, int stride,
                                               u16* __restrict__ Vpk) {
    __shared__ u16 tile[32][33];
    int b = blockIdx.z;
    int n0 = blockIdx.x * 32, vc0 = blockIdx.y * 32;  // vc0 in [0,256)
    int h = vc0 >> 6, dl = vc0 & 63;
    int bh = b * 4 + h;
    int kb = n0 >> 6, kc = (n0 >> 5) & 1;
    int tx = threadIdx.x, ty = threadIdx.y;
#pragma unroll
    for (int i = 0; i < 4; i++)
        tile[ty + i * 8][tx] =
            src[(size_t)(b * N_ + n0 + ty + i * 8) * stride + vc0 + tx];
    __syncthreads();
    int g = (tx >> 3) & 3, j = tx & 7;
#pragma unroll
    for (int i = 0; i < 4; i++) {
        int cl = ty + i * 8;            // d-local 0..31
        int d = dl + cl;
        int dt = d >> 4;
        int lane = (d & 15) + 16 * g;
        size_t addr = ((size_t)(bh * 16 + kb) * 8 + kc * 4 + dt) * 512 + lane * 8 + j;
        Vpk[addr] = tile[tx][cl];
    }
}

// -------- MFMA GEMM (m97-style): linear LDS + global_load_lds width-16 --------
// A rows stride astr, C rows stride ldc. Tile 128x128, BK=32, 4 waves.
__global__ __launch_bounds__(256) void k_gemm_bf16(const u16* __restrict__ A, int astr,
                                                   const u16* __restrict__ W,
                                                   const float* __restrict__ bias,
                                                   u16* __restrict__ C,
                                                   int Nout, int ldc) {
    __shared__ u16 As[128 * 32];
    __shared__ u16 Bs[128 * 32];
    int m0 = blockIdx.y * 128, n0 = blockIdx.x * 128;
    int t = threadIdx.x;
    int wid = t >> 6, lane = t & 63;
    int l16 = lane & 15, g = lane >> 4;
    int wm = (wid >> 1) * 64, wn = (wid & 1) * 64;
    int srow0 = (lane >> 2);
    int scol = (lane & 3) * 8;
    f32x4 zz = {0.f, 0.f, 0.f, 0.f};
    f32x4 acc[4][4];
#pragma unroll
    for (int i = 0; i < 4; i++)
#pragma unroll
        for (int j = 0; j < 4; j++) acc[i][j] = zz;
    for (int k0 = 0; k0 < 256; k0 += 32) {
        __syncthreads();
#pragma unroll
        for (int i = 0; i < 2; i++) {
            int rr = (wid * 2 + i) * 16;
            gl_lds16(A + (size_t)(m0 + rr + srow0) * astr + k0 + scol, &As[rr * 32]);
            gl_lds16(W + (size_t)(n0 + rr + srow0) * 256 + k0 + scol, &Bs[rr * 32]);
        }
        __syncthreads();
        bf16x8 af[4], bfr[4];
#pragma unroll
        for (int mt = 0; mt < 4; mt++)
            af[mt] = *reinterpret_cast<const bf16x8*>(&As[(wm + mt * 16 + l16) * 32 + g * 8]);
#pragma unroll
        for (int nt = 0; nt < 4; nt++)
            bfr[nt] = *reinterpret_cast<const bf16x8*>(&Bs[(wn + nt * 16 + l16) * 32 + g * 8]);
#pragma unroll
        for (int mt = 0; mt < 4; mt++)
#pragma unroll
            for (int nt = 0; nt < 4; nt++)
                acc[mt][nt] = __builtin_amdgcn_mfma_f32_16x16x32_bf16(
                    af[mt], bfr[nt], acc[mt][nt], 0, 0, 0);
    }
    float bval[4];
#pragma unroll
    for (int nt = 0; nt < 4; nt++) {
        int n = n0 + wn + nt * 16 + l16;
        bval[nt] = bias ? bias[n] : 0.0f;
    }
#pragma unroll
    for (int mt = 0; mt < 4; mt++)
#pragma unroll
        for (int r = 0; r < 4; r++) {
            int m = m0 + wm + mt * 16 + g * 4 + r;
#pragma unroll
            for (int nt = 0; nt < 4; nt++) {
                int n = n0 + wn + nt * 16 + l16;
                C[(size_t)m * ldc + n] = f2bf(acc[mt][nt][r] + bval[nt]);
            }
        }
}

// ------- depthwise 3x3 conv + bias + residual, vectorized (short8/lane) -------
__global__ __launch_bounds__(256) void k_dwconv_add(const u16* __restrict__ yp,
                                                    const float* __restrict__ wT,
                                                    const float* __restrict__ dw_b,
                                                    u16* __restrict__ out) {
    int b = blockIdx.y;
    int px = blockIdx.x * 8 + (threadIdx.x >> 5);
    int cc0 = (threadIdx.x & 31) * 8;
    int yy = px >> 5, xx = px & 31;
    const u16* ypb = yp + (size_t)b * N_ * C_;
    float acc[8];
    {
        float4 b0 = *reinterpret_cast<const float4*>(&dw_b[cc0]);
        float4 b1 = *reinterpret_cast<const float4*>(&dw_b[cc0 + 4]);
        acc[0] = b0.x; acc[1] = b0.y; acc[2] = b0.z; acc[3] = b0.w;
        acc[4] = b1.x; acc[5] = b1.y; acc[6] = b1.z; acc[7] = b1.w;
    }
#pragma unroll
    for (int dy = 0; dy < 3; dy++) {
        int y2 = yy + dy - 1;
        if (y2 < 0 || y2 >= 32) continue;
#pragma unroll
        for (int dx = 0; dx < 3; dx++) {
            int x2 = xx + dx - 1;
            if (x2 < 0 || x2 >= 32) continue;
            int tap = dy * 3 + dx;
            bf16x8 v = *reinterpret_cast<const bf16x8*>(
                &ypb[(size_t)(y2 * 32 + x2) * C_ + cc0]);
            float4 w0 = *reinterpret_cast<const float4*>(&wT[tap * 256 + cc0]);
            float4 w1 = *reinterpret_cast<const float4*>(&wT[tap * 256 + cc0 + 4]);
            acc[0] += bf2f((u16)v[0]) * w0.x;
            acc[1] += bf2f((u16)v[1]) * w0.y;
            acc[2] += bf2f((u16)v[2]) * w0.z;
            acc[3] += bf2f((u16)v[3]) * w0.w;
            acc[4] += bf2f((u16)v[4]) * w1.x;
            acc[5] += bf2f((u16)v[5]) * w1.y;
            acc[6] += bf2f((u16)v[6]) * w1.z;
            acc[7] += bf2f((u16)v[7]) * w1.w;
        }
    }
    bf16x8 ctr = *reinterpret_cast<const bf16x8*>(&ypb[(size_t)px * C_ + cc0]);
    bf16x8 o;
#pragma unroll
    for (int j = 0; j < 8; j++)
        o[j] = (short)f2bf(acc[j] + bf2f((u16)ctr[j]));
    *reinterpret_cast<bf16x8*>(&out[((size_t)b * N_ + px) * C_ + cc0]) = o;
}

// -------- MFMA flash attention: all-register P, packed K/V, 4-way kv-split ----
// Block = 4 waves over the SAME 32 q-rows; wave wv covers kv tiles
// [wv*4, wv*4+4). No-max softmax partials combine linearly via a 2-stage LDS
// tree reduce. Grid 2048; launch_bounds min-waves kept at 4 (NOT 6): R14 showed
// forcing 6 caps VGPR at 40 < ~80 live regs -> scratch spill -> 1.5GB traffic.
template <int STAGE>
__global__ __launch_bounds__(256, 4) void k_attn_mfma(const u16* __restrict__ Q, int qstr,
                                                      const u16* __restrict__ Kpk,
                                                      const u16* __restrict__ Vpk,
                                                      void* __restrict__ outp, int ostr) {
    __shared__ union { float Cmb[2][64][33]; float Os[32][68]; } sm;
    __shared__ float Clsum[2][64][2];
    int cid = blockIdx.x;
    int xcd = cid & 7, slot = cid >> 3;  // slot in [0,256)
    int bh = xcd * 8 + (slot & 7);       // 64 (b,h) panels, 8 per XCD
    int qc = slot >> 3;                  // q-chunk 0..31 (32 rows each)
    int h = bh & 3, b = bh >> 2;
    int t = threadIdx.x;
    int wv = t >> 6, lane = t & 63;      // wv = kv quarter
    int l16 = lane & 15, g = lane >> 4, g8 = g * 8;

    const float SCL = 0.18033688011112042f;  // 0.125*log2(e)
    const u16* Qb =
        Q + ((size_t)(b * N_ + qc * 32 + l16)) * qstr + h * 64 + g8;
    bf16x8 qf[2][2];
#pragma unroll
    for (int qg = 0; qg < 2; qg++)
#pragma unroll
        for (int w2 = 0; w2 < 2; w2++) {
            qf[qg][w2] = *reinterpret_cast<const bf16x8*>(Qb + qg * 16 * qstr + w2 * 32);
#pragma unroll
            for (int j = 0; j < 8; j++)
                qf[qg][w2][j] = (short)f2bf(bf2f((u16)qf[qg][w2][j]) * SCL);
        }

    const u16* Kp = Kpk + (size_t)bh * 65536 + lane * 8;
    const u16* Vp = Vpk + (size_t)bh * 65536 + lane * 8;

    int kb0 = wv * 4, kb1 = kb0 + 4;
    bf16x8 kf[4][2];
#pragma unroll
    for (int nt = 0; nt < 4; nt++)
#pragma unroll
        for (int w2 = 0; w2 < 2; w2++)
            kf[nt][w2] = *reinterpret_cast<const bf16x8*>(
                Kp + (size_t)(kb0 * 8 + nt * 2 + w2) * 512);

    f32x4 zz = {0.f, 0.f, 0.f, 0.f};
    f32x4 accO[4][2];
#pragma unroll
    for (int dt = 0; dt < 4; dt++)
#pragma unroll
        for (int qg = 0; qg < 2; qg++) accO[dt][qg] = zz;
    float lsum[2] = {0.f, 0.f};
    int pwv[2][8];

    for (int kb = kb0; kb < kb1; kb++) {
        bf16x8 vf[2][4];
#pragma unroll
        for (int kc = 0; kc < 2; kc++)
#pragma unroll
            for (int dt = 0; dt < 4; dt++)
                vf[kc][dt] = *reinterpret_cast<const bf16x8*>(
                    Vp + (size_t)(kb * 8 + kc * 4 + dt) * 512);
#pragma unroll
        for (int qg = 0; qg < 2; qg++) {
            f32x4 st[4];
#pragma unroll
            for (int nt = 0; nt < 4; nt++) st[nt] = zz;
#pragma unroll
            for (int nt = 0; nt < 4; nt++) {
                st[nt] = __builtin_amdgcn_mfma_f32_16x16x32_bf16(kf[nt][0], qf[qg][0],
                                                                 st[nt], 0, 0, 0);
                st[nt] = __builtin_amdgcn_mfma_f32_16x16x32_bf16(kf[nt][1], qf[qg][1],
                                                                 st[nt], 0, 0, 0);
            }
#pragma unroll
            for (int nt = 0; nt < 4; nt++) {
                float p0 = EXP2(st[nt][0]);
                float p1 = EXP2(st[nt][1]);
                float p2 = EXP2(st[nt][2]);
                float p3 = EXP2(st[nt][3]);
                lsum[qg] += (p0 + p1) + (p2 + p3);
                pwv[qg][nt * 2 + 0] = (int)pack2bf(p0, p1);
                pwv[qg][nt * 2 + 1] = (int)pack2bf(p2, p3);
            }
        }
        {
            int nkb = (kb < kb1 - 1) ? kb + 1 : kb;
#pragma unroll
            for (int nt = 0; nt < 4; nt++)
#pragma unroll
                for (int w2 = 0; w2 < 2; w2++)
                    kf[nt][w2] = *reinterpret_cast<const bf16x8*>(
                        Kp + (size_t)(nkb * 8 + nt * 2 + w2) * 512);
        }
#pragma unroll
        for (int qg = 0; qg < 2; qg++)
#pragma unroll
            for (int kc = 0; kc < 2; kc++) {
                union { int i[4]; bf16x8 v; } u;
                u.i[0] = pwv[qg][4 * kc + 0];
                u.i[1] = pwv[qg][4 * kc + 1];
                u.i[2] = pwv[qg][4 * kc + 2];
                u.i[3] = pwv[qg][4 * kc + 3];
#pragma unroll
                for (int dt = 0; dt < 4; dt++)
                    accO[dt][qg] = __builtin_amdgcn_mfma_f32_16x16x32_bf16(
                        vf[kc][dt], u.v, accO[dt][qg], 0, 0, 0);
            }
    }

    // ---- 2-stage tree reduce across kv quarters (linear partials) ----
    if (wv & 1) {
#pragma unroll
        for (int dt = 0; dt < 4; dt++)
#pragma unroll
            for (int qg = 0; qg < 2; qg++)
#pragma unroll
                for (int r = 0; r < 4; r++)
                    sm.Cmb[wv >> 1][lane][(dt * 2 + qg) * 4 + r] = accO[dt][qg][r];
        Clsum[wv >> 1][lane][0] = lsum[0];
        Clsum[wv >> 1][lane][1] = lsum[1];
    }
    __syncthreads();
    if (!(wv & 1)) {
#pragma unroll
        for (int dt = 0; dt < 4; dt++)
#pragma unroll
            for (int qg = 0; qg < 2; qg++)
#pragma unroll
                for (int r = 0; r < 4; r++)
                    accO[dt][qg][r] += sm.Cmb[wv >> 1][lane][(dt * 2 + qg) * 4 + r];
        lsum[0] += Clsum[wv >> 1][lane][0];
        lsum[1] += Clsum[wv >> 1][lane][1];
    }
    __syncthreads();
    if (wv == 2) {
#pragma unroll
        for (int dt = 0; dt < 4; dt++)
#pragma unroll
            for (int qg = 0; qg < 2; qg++)
#pragma unroll
                for (int r = 0; r < 4; r++)
                    sm.Cmb[0][lane][(dt * 2 + qg) * 4 + r] = accO[dt][qg][r];
        Clsum[0][lane][0] = lsum[0];
        Clsum[0][lane][1] = lsum[1];
    }
    __syncthreads();
    if (wv == 0) {
#pragma unroll
        for (int dt = 0; dt < 4; dt++)
#pragma unroll
            for (int qg = 0; qg < 2; qg++)
#pragma unroll
                for (int r = 0; r < 4; r++)
                    accO[dt][qg][r] += sm.Cmb[0][lane][(dt * 2 + qg) * 4 + r];
        lsum[0] += Clsum[0][lane][0];
        lsum[1] += Clsum[0][lane][1];
        float inv[2];
#pragma unroll
        for (int qg = 0; qg < 2; qg++) {
            float l = lsum[qg];
            l += __shfl_xor(l, 16);
            l += __shfl_xor(l, 32);
            inv[qg] = 1.0f / l;
        }
        if constexpr (STAGE == 0) {
            u16* O = (u16*)outp;
            size_t rowb = (size_t)(b * N_ + qc * 32 + l16);
#pragma unroll
            for (int qg = 0; qg < 2; qg++)
#pragma unroll
                for (int dt = 0; dt < 4; dt++) {
                    ushort4 o;
                    o.x = f2bf(accO[dt][qg][0] * inv[qg]);
                    o.y = f2bf(accO[dt][qg][1] * inv[qg]);
                    o.z = f2bf(accO[dt][qg][2] * inv[qg]);
                    o.w = f2bf(accO[dt][qg][3] * inv[qg]);
                    *reinterpret_cast<ushort4*>(
                        &O[(rowb + qg * 16) * ostr + h * 64 + dt * 16 + g * 4]) = o;
                }
        } else {
            __builtin_amdgcn_s_barrier();  // wait: others done reading Cmb
#pragma unroll
            for (int qg = 0; qg < 2; qg++)
#pragma unroll
                for (int dt = 0; dt < 4; dt++)
#pragma unroll
                    for (int r = 0; r < 4; r++)
                        sm.Os[qg * 16 + l16][dt * 16 + g * 4 + r] = accO[dt][qg][r] * inv[qg];
        }
    } else if constexpr (STAGE == 1) {
        __builtin_amdgcn_s_barrier();  // match wave-0 barrier
    }
    if constexpr (STAGE == 1) {
        __syncthreads();
        // batch-mixing scatter: n = qc*32+row; bo=(n&1)*8+h*2+(b>>3),
        // co=((n>>1)&3)*64+d, no=(b&7)*128+(n>>3); row = j*8+(q2*2+tl), j=0..3
        float* out = (float*)outp;
#pragma unroll
        for (int e = 0; e < 2; e++) {
            int seg = t + e * 256;          // 512 segs = 64 d x 8 (tl,q2)
            int d = seg & 63, tb = seg >> 6;
            int tl = tb & 1, q2 = (tb >> 1) & 3;
            int bo = tl * 8 + h * 2 + (b >> 3);
            int co = q2 * 64 + d;
            size_t base = (size_t)bo * (C_ * N_) + (size_t)co * N_ + (b & 7) * 128 + qc * 4;
            float4 v;
            v.x = sm.Os[0 * 8 + q2 * 2 + tl][d];
            v.y = sm.Os[1 * 8 + q2 * 2 + tl][d];
            v.z = sm.Os[2 * 8 + q2 * 2 + tl][d];
            v.w = sm.Os[3 * 8 + q2 * 2 + tl][d];
            *reinterpret_cast<float4*>(&out[base]) = v;
        }
    }
}

extern "C" void kernel_launch(void* const* d_in, const int* in_sizes, int n_in,
                              void* d_out, int out_size, void* d_ws, size_t ws_size,
                              hipStream_t stream) {
    const float* x      = (const float*)d_in[0];
    const float* q_w    = (const float*)d_in[1];
    const float* kv_w   = (const float*)d_in[2];
    const float* proj_w = (const float*)d_in[3];
    const float* proj_b = (const float*)d_in[4];
    const float* lq_w   = (const float*)d_in[5];
    const float* lq_b   = (const float*)d_in[6];
    const float* lkv_w  = (const float*)d_in[7];
    const float* lkv_b  = (const float*)d_in[8];
    // d_in[9] = rel_bias: constant along softmax axis -> exact no-op
    const float* dw_w   = (const float*)d_in[10];
    const float* dw_b   = (const float*)d_in[11];

    const size_t SZ = (size_t)B_ * N_ * C_;  // 4M elems
    u16* ws = (u16*)d_ws;
    u16* xf    = ws;              // [0,SZ): xf, later s2in
    u16* qkv   = ws + SZ;         // [SZ,4SZ): ldc=768: q/q2 | K | V columns
    u16* Kpk   = ws + 4 * SZ;     // [4SZ,5SZ): packed K, also ypb between stages
    u16* Vpk   = ws + 5 * SZ;     // [5SZ,6SZ): packed V
    u16* arena = ws + 6 * SZ;     // weights: wq|wkv|wlq|wproj|wlkv
    u16* wfused = arena;          // wq|wkv stacked: [768][256]
    u16* wlq    = arena + 196608;
    u16* wproj  = arena + 262144;
    u16* wlkv   = arena + 327680;
    float* wT   = (float*)(arena + 458752);  // [9][256] f32 transposed dw weights
    u16* yb     = qkv + 256;      // attn1 out in dead K columns (stride 768)
    u16* ypb    = Kpk;            // proj out in dead packed-K slot
    u16* s2in   = xf;             // conv+res out in dead xf slot

    k_f2bf5<<<449, 256, 0, stream>>>(q_w, kv_w, lq_w, proj_w, lkv_w, arena, dw_w, wT);
    k_transpose_x<<<dim3(32, 8, B_), dim3(32, 8), 0, stream>>>(x, xf);
    // fused q|kv projections (no bias on either)
    k_gemm_bf16<<<dim3(6, 128), 256, 0, stream>>>(xf, 256, wfused, nullptr, qkv, 768, 768);
    k_packK<<<2048, 256, 0, stream>>>(qkv + 256, 768, Kpk);
    k_packV<<<dim3(32, 8, B_), dim3(32, 8), 0, stream>>>(qkv + 512, 768, Vpk);
    k_attn_mfma<0><<<2048, 256, 0, stream>>>(qkv, 768, Kpk, Vpk, yb, 768);
    // q2 projection into the now-dead q columns
    k_gemm_bf16<<<dim3(2, 128), 256, 0, stream>>>(xf, 256, wlq, lq_b, qkv, 256, 768);
    k_gemm_bf16<<<dim3(2, 128), 256, 0, stream>>>(yb, 768, wproj, proj_b, ypb, 256, 256);
    k_dwconv_add<<<dim3(128, B_), 256, 0, stream>>>(ypb, wT, dw_b, s2in);
    k_gemm_bf16<<<dim3(4, 128), 256, 0, stream>>>(s2in, 256, wlkv, lkv_b, qkv + 256, 512, 768);
    k_packK<<<2048, 256, 0, stream>>>(qkv + 256, 768, Kpk);
    k_packV<<<dim3(32, 8, B_), dim3(32, 8), 0, stream>>>(qkv + 512, 768, Vpk);
    k_attn_mfma<1><<<2048, 256, 0, stream>>>(qkv, 768, Kpk, Vpk, d_out, 0);
}

// Round 16
// 144.542 us; speedup vs baseline: 6.1129x; 2.7877x over previous
//
#include <hip/hip_runtime.h>
#include <hip/hip_bf16.h>

#define B_  16
#define C_  256
#define N_  1024
#define H_  4

typedef unsigned short u16;
typedef __attribute__((ext_vector_type(8))) short bf16x8;
typedef __attribute__((ext_vector_type(4))) float f32x4;

#if __has_builtin(__builtin_amdgcn_exp2f)
#define EXP2(x) __builtin_amdgcn_exp2f(x)
#else
#define EXP2(x) __builtin_exp2f(x)
#endif

__device__ __forceinline__ u16 f2bf(float f) {
    union { float f; unsigned u; } v; v.f = f;
    unsigned r = v.u + 0x7FFFu + ((v.u >> 16) & 1u);
    return (u16)(r >> 16);
}
__device__ __forceinline__ float bf2f(u16 h) {
    union { unsigned u; float f; } v; v.u = ((unsigned)h) << 16;
    return v.f;
}
__device__ __forceinline__ unsigned pack2bf(float a, float b) {
    __hip_bfloat162 h = __float22bfloat162_rn(make_float2(a, b));
    union { __hip_bfloat162 h2; unsigned u; } cv; cv.h2 = h;
    return cv.u;
}
// async global->LDS, 16B per lane; lds base must be wave-uniform
__device__ __forceinline__ void gl_lds16(const u16* g, u16* l) {
    __builtin_amdgcn_global_load_lds(
        (const __attribute__((address_space(1))) void*)g,
        (__attribute__((address_space(3))) void*)l, 16, 0, 0);
}

// ---- weights f32->bf16 arena (wq|wkv|wlq|wproj|wlkv) + dw weight transpose ----
__global__ __launch_bounds__(256) void k_f2bf5(const float* __restrict__ a0,
                                               const float* __restrict__ a1,
                                               const float* __restrict__ a2,
                                               const float* __restrict__ a3,
                                               const float* __restrict__ a4,
                                               u16* __restrict__ dst,
                                               const float* __restrict__ dw_w,
                                               float* __restrict__ wT) {
    if (blockIdx.x == 448) {  // dw weights [256][9] -> [9][256]
        int i = threadIdx.x;
#pragma unroll
        for (int tap = 0; tap < 9; tap++)
            wT[tap * 256 + i] = dw_w[i * 9 + tap];
        return;
    }
    int i = blockIdx.x * 256 + threadIdx.x;  // float4 index, total 114688
    const float* s; int off;
    if (i < 16384)      { s = a0; off = 0; }
    else if (i < 49152) { s = a1; off = 16384; }
    else if (i < 65536) { s = a2; off = 49152; }
    else if (i < 81920) { s = a3; off = 65536; }
    else                { s = a4; off = 81920; }
    float4 v = reinterpret_cast<const float4*>(s)[i - off];
    ushort4 o;
    o.x = f2bf(v.x); o.y = f2bf(v.y); o.z = f2bf(v.z); o.w = f2bf(v.w);
    reinterpret_cast<ushort4*>(dst)[i] = o;
}

// ---------------- x[b][c][n] f32 -> xf[b][n][c] bf16 ----------------
__global__ __launch_bounds__(256) void k_transpose_x(const float* __restrict__ x,
                                                     u16* __restrict__ xf) {
    __shared__ u16 tile[32][33];
    int b = blockIdx.z;
    int n0 = blockIdx.x * 32, c0 = blockIdx.y * 32;
    int tx = threadIdx.x, ty = threadIdx.y;  // 32 x 8
#pragma unroll
    for (int i = 0; i < 4; i++)
        tile[ty + i * 8][tx] =
            f2bf(x[((size_t)(b * C_ + c0 + ty + i * 8)) * N_ + n0 + tx]);
    __syncthreads();
#pragma unroll
    for (int i = 0; i < 4; i++)
        xf[((size_t)(b * N_ + n0 + ty + i * 8)) * C_ + c0 + tx] = tile[tx][ty + i * 8];
}

// ---- pack K into MFMA-fragment chunk order (rperm baked in); coalesced stores ----
__global__ __launch_bounds__(256) void k_packK(const u16* __restrict__ Ksrc, int kstr,
                                               u16* __restrict__ Kpk) {
    int tid = blockIdx.x * 256 + threadIdx.x;  // 524288 total
    int lane = tid & 63;
    int chunk = tid >> 6;                      // 8192 chunks
    int c = chunk & 7;
    int kb = (chunk >> 3) & 15;
    int bh = chunk >> 7;                       // b*4+h
    int h = bh & 3, b = bh >> 2;
    int nt = c >> 1, w2 = c & 1;
    int l16 = lane & 15, g = lane >> 4;
    int rn = kb * 64 + (nt >> 1) * 32 + (nt & 1) * 4 + (((l16 & 12) << 1) | (l16 & 3));
    const u16* src = Ksrc + (size_t)(b * N_ + rn) * kstr + h * 64 + w2 * 32 + g * 8;
    *reinterpret_cast<bf16x8*>(&Kpk[(size_t)chunk * 512 + lane * 8]) =
        *reinterpret_cast<const bf16x8*>(src);
}

// ---- pack V^T into MFMA-fragment chunk order ----
__global__ __launch_bounds__(256) void k_packV(const u16* __restrict__ src, int stride,
                                               u16* __restrict__ Vpk) {
    __shared__ u16 tile[32][33];
    int b = blockIdx.z;
    int n0 = blockIdx.x * 32, vc0 = blockIdx.y * 32;  // vc0 in [0,256)
    int h = vc0 >> 6, dl = vc0 & 63;
    int bh = b * 4 + h;
    int kb = n0 >> 6, kc = (n0 >> 5) & 1;
    int tx = threadIdx.x, ty = threadIdx.y;
#pragma unroll
    for (int i = 0; i < 4; i++)
        tile[ty + i * 8][tx] =
            src[(size_t)(b * N_ + n0 + ty + i * 8) * stride + vc0 + tx];
    __syncthreads();
    int g = (tx >> 3) & 3, j = tx & 7;
#pragma unroll
    for (int i = 0; i < 4; i++) {
        int cl = ty + i * 8;            // d-local 0..31
        int d = dl + cl;
        int dt = d >> 4;
        int lane = (d & 15) + 16 * g;
        size_t addr = ((size_t)(bh * 16 + kb) * 8 + kc * 4 + dt) * 512 + lane * 8 + j;
        Vpk[addr] = tile[tx][cl];
    }
}

// -------- MFMA GEMM (m97-style): linear LDS + global_load_lds width-16 --------
// A rows stride astr, C rows stride ldc. Tile 128x128, BK=32, 4 waves.
// bias applies to cols n >= bofs as bias[n-bofs].
__global__ __launch_bounds__(256) void k_gemm_bf16(const u16* __restrict__ A, int astr,
                                                   const u16* __restrict__ W,
                                                   const float* __restrict__ bias,
                                                   int bofs, u16* __restrict__ C,
                                                   int Nout, int ldc) {
    __shared__ u16 As[128 * 32];
    __shared__ u16 Bs[128 * 32];
    int m0 = blockIdx.y * 128, n0 = blockIdx.x * 128;
    int t = threadIdx.x;
    int wid = t >> 6, lane = t & 63;
    int l16 = lane & 15, g = lane >> 4;
    int wm = (wid >> 1) * 64, wn = (wid & 1) * 64;
    int srow0 = (lane >> 2);
    int scol = (lane & 3) * 8;
    f32x4 zz = {0.f, 0.f, 0.f, 0.f};
    f32x4 acc[4][4];
#pragma unroll
    for (int i = 0; i < 4; i++)
#pragma unroll
        for (int j = 0; j < 4; j++) acc[i][j] = zz;
    for (int k0 = 0; k0 < 256; k0 += 32) {
        __syncthreads();
#pragma unroll
        for (int i = 0; i < 2; i++) {
            int rr = (wid * 2 + i) * 16;
            gl_lds16(A + (size_t)(m0 + rr + srow0) * astr + k0 + scol, &As[rr * 32]);
            gl_lds16(W + (size_t)(n0 + rr + srow0) * 256 + k0 + scol, &Bs[rr * 32]);
        }
        __syncthreads();
        bf16x8 af[4], bfr[4];
#pragma unroll
        for (int mt = 0; mt < 4; mt++)
            af[mt] = *reinterpret_cast<const bf16x8*>(&As[(wm + mt * 16 + l16) * 32 + g * 8]);
#pragma unroll
        for (int nt = 0; nt < 4; nt++)
            bfr[nt] = *reinterpret_cast<const bf16x8*>(&Bs[(wn + nt * 16 + l16) * 32 + g * 8]);
#pragma unroll
        for (int mt = 0; mt < 4; mt++)
#pragma unroll
            for (int nt = 0; nt < 4; nt++)
                acc[mt][nt] = __builtin_amdgcn_mfma_f32_16x16x32_bf16(
                    af[mt], bfr[nt], acc[mt][nt], 0, 0, 0);
    }
    float bval[4];
#pragma unroll
    for (int nt = 0; nt < 4; nt++) {
        int n = n0 + wn + nt * 16 + l16;
        bval[nt] = (bias && n >= bofs) ? bias[n - bofs] : 0.0f;
    }
#pragma unroll
    for (int mt = 0; mt < 4; mt++)
#pragma unroll
        for (int r = 0; r < 4; r++) {
            int m = m0 + wm + mt * 16 + g * 4 + r;
#pragma unroll
            for (int nt = 0; nt < 4; nt++) {
                int n = n0 + wn + nt * 16 + l16;
                C[(size_t)m * ldc + n] = f2bf(acc[mt][nt][r] + bval[nt]);
            }
        }
}

// ------- depthwise 3x3 conv + bias + residual, vectorized (short8/lane) -------
__global__ __launch_bounds__(256) void k_dwconv_add(const u16* __restrict__ yp,
                                                    const float* __restrict__ wT,
                                                    const float* __restrict__ dw_b,
                                                    u16* __restrict__ out) {
    int b = blockIdx.y;
    int px = blockIdx.x * 8 + (threadIdx.x >> 5);
    int cc0 = (threadIdx.x & 31) * 8;
    int yy = px >> 5, xx = px & 31;
    const u16* ypb = yp + (size_t)b * N_ * C_;
    float acc[8];
    {
        float4 b0 = *reinterpret_cast<const float4*>(&dw_b[cc0]);
        float4 b1 = *reinterpret_cast<const float4*>(&dw_b[cc0 + 4]);
        acc[0] = b0.x; acc[1] = b0.y; acc[2] = b0.z; acc[3] = b0.w;
        acc[4] = b1.x; acc[5] = b1.y; acc[6] = b1.z; acc[7] = b1.w;
    }
#pragma unroll
    for (int dy = 0; dy < 3; dy++) {
        int y2 = yy + dy - 1;
        if (y2 < 0 || y2 >= 32) continue;
#pragma unroll
        for (int dx = 0; dx < 3; dx++) {
            int x2 = xx + dx - 1;
            if (x2 < 0 || x2 >= 32) continue;
            int tap = dy * 3 + dx;
            bf16x8 v = *reinterpret_cast<const bf16x8*>(
                &ypb[(size_t)(y2 * 32 + x2) * C_ + cc0]);
            float4 w0 = *reinterpret_cast<const float4*>(&wT[tap * 256 + cc0]);
            float4 w1 = *reinterpret_cast<const float4*>(&wT[tap * 256 + cc0 + 4]);
            acc[0] += bf2f((u16)v[0]) * w0.x;
            acc[1] += bf2f((u16)v[1]) * w0.y;
            acc[2] += bf2f((u16)v[2]) * w0.z;
            acc[3] += bf2f((u16)v[3]) * w0.w;
            acc[4] += bf2f((u16)v[4]) * w1.x;
            acc[5] += bf2f((u16)v[5]) * w1.y;
            acc[6] += bf2f((u16)v[6]) * w1.z;
            acc[7] += bf2f((u16)v[7]) * w1.w;
        }
    }
    bf16x8 ctr = *reinterpret_cast<const bf16x8*>(&ypb[(size_t)px * C_ + cc0]);
    bf16x8 o;
#pragma unroll
    for (int j = 0; j < 8; j++)
        o[j] = (short)f2bf(acc[j] + bf2f((u16)ctr[j]));
    *reinterpret_cast<bf16x8*>(&out[((size_t)b * N_ + px) * C_ + cc0]) = o;
}

// ---------------- MFMA flash attention: all-register P, packed K/V ------------
// R13-proven structure: block = 4 waves over 64 q-rows, wave (qpair, kvh) does
// 32 q-rows x 8 kv tiles; 2-way kv-split partials combine via LDS. Grid 1024.
// No setprio (R11/R12 lesson); launch_bounds (256,4) (R14/R15 spill lesson).
template <int STAGE>
__global__ __launch_bounds__(256, 4) void k_attn_mfma(const u16* __restrict__ Q, int qstr,
                                                      const u16* __restrict__ Kpk,
                                                      const u16* __restrict__ Vpk,
                                                      void* __restrict__ outp, int ostr) {
    __shared__ float Cmb[2][64][33];
    __shared__ float Clsum[2][64][2];
    int cid = blockIdx.x;
    int xcd = cid & 7, slot = cid >> 3;  // slot in [0,128)
    int bh = xcd * 8 + (slot & 7);       // 64 (b,h) panels, 8 per XCD
    int qc = slot >> 3;                  // q-chunk 0..15 (64 rows each)
    int h = bh & 3, b = bh >> 2;
    int t = threadIdx.x;
    int wv = t >> 6, lane = t & 63;
    int qpair = wv >> 1, kvh = wv & 1;
    int l16 = lane & 15, g = lane >> 4, g8 = g * 8;

    const float SCL = 0.18033688011112042f;  // 0.125*log2(e)
    const u16* Qb =
        Q + ((size_t)(b * N_ + qc * 64 + qpair * 32 + l16)) * qstr + h * 64 + g8;
    bf16x8 qf[2][2];
#pragma unroll
    for (int qg = 0; qg < 2; qg++)
#pragma unroll
        for (int w2 = 0; w2 < 2; w2++) {
            qf[qg][w2] = *reinterpret_cast<const bf16x8*>(Qb + qg * 16 * qstr + w2 * 32);
#pragma unroll
            for (int j = 0; j < 8; j++)
                qf[qg][w2][j] = (short)f2bf(bf2f((u16)qf[qg][w2][j]) * SCL);
        }

    const u16* Kp = Kpk + (size_t)bh * 65536 + lane * 8;
    const u16* Vp = Vpk + (size_t)bh * 65536 + lane * 8;

    int kb0 = kvh * 8, kb1 = kb0 + 8;
    bf16x8 kf[4][2];
#pragma unroll
    for (int nt = 0; nt < 4; nt++)
#pragma unroll
        for (int w2 = 0; w2 < 2; w2++)
            kf[nt][w2] = *reinterpret_cast<const bf16x8*>(
                Kp + (size_t)(kb0 * 8 + nt * 2 + w2) * 512);

    f32x4 zz = {0.f, 0.f, 0.f, 0.f};
    f32x4 accO[4][2];
#pragma unroll
    for (int dt = 0; dt < 4; dt++)
#pragma unroll
        for (int qg = 0; qg < 2; qg++) accO[dt][qg] = zz;
    float lsum[2] = {0.f, 0.f};
    int pwv[2][8];

    for (int kb = kb0; kb < kb1; kb++) {
        bf16x8 vf[2][4];
#pragma unroll
        for (int kc = 0; kc < 2; kc++)
#pragma unroll
            for (int dt = 0; dt < 4; dt++)
                vf[kc][dt] = *reinterpret_cast<const bf16x8*>(
                    Vp + (size_t)(kb * 8 + kc * 4 + dt) * 512);
#pragma unroll
        for (int qg = 0; qg < 2; qg++) {
            f32x4 st[4];
#pragma unroll
            for (int nt = 0; nt < 4; nt++) st[nt] = zz;
#pragma unroll
            for (int nt = 0; nt < 4; nt++) {
                st[nt] = __builtin_amdgcn_mfma_f32_16x16x32_bf16(kf[nt][0], qf[qg][0],
                                                                 st[nt], 0, 0, 0);
                st[nt] = __builtin_amdgcn_mfma_f32_16x16x32_bf16(kf[nt][1], qf[qg][1],
                                                                 st[nt], 0, 0, 0);
            }
#pragma unroll
            for (int nt = 0; nt < 4; nt++) {
                float p0 = EXP2(st[nt][0]);
                float p1 = EXP2(st[nt][1]);
                float p2 = EXP2(st[nt][2]);
                float p3 = EXP2(st[nt][3]);
                lsum[qg] += (p0 + p1) + (p2 + p3);
                pwv[qg][nt * 2 + 0] = (int)pack2bf(p0, p1);
                pwv[qg][nt * 2 + 1] = (int)pack2bf(p2, p3);
            }
        }
        {
            int nkb = (kb < kb1 - 1) ? kb + 1 : kb;
#pragma unroll
            for (int nt = 0; nt < 4; nt++)
#pragma unroll
                for (int w2 = 0; w2 < 2; w2++)
                    kf[nt][w2] = *reinterpret_cast<const bf16x8*>(
                        Kp + (size_t)(nkb * 8 + nt * 2 + w2) * 512);
        }
#pragma unroll
        for (int qg = 0; qg < 2; qg++)
#pragma unroll
            for (int kc = 0; kc < 2; kc++) {
                union { int i[4]; bf16x8 v; } u;
                u.i[0] = pwv[qg][4 * kc + 0];
                u.i[1] = pwv[qg][4 * kc + 1];
                u.i[2] = pwv[qg][4 * kc + 2];
                u.i[3] = pwv[qg][4 * kc + 3];
#pragma unroll
                for (int dt = 0; dt < 4; dt++)
                    accO[dt][qg] = __builtin_amdgcn_mfma_f32_16x16x32_bf16(
                        vf[kc][dt], u.v, accO[dt][qg], 0, 0, 0);
            }
    }

    if (kvh == 1) {
#pragma unroll
        for (int dt = 0; dt < 4; dt++)
#pragma unroll
            for (int qg = 0; qg < 2; qg++)
#pragma unroll
                for (int r = 0; r < 4; r++)
                    Cmb[qpair][lane][(dt * 2 + qg) * 4 + r] = accO[dt][qg][r];
        Clsum[qpair][lane][0] = lsum[0];
        Clsum[qpair][lane][1] = lsum[1];
    }
    __syncthreads();
    if (kvh == 0) {
#pragma unroll
        for (int dt = 0; dt < 4; dt++)
#pragma unroll
            for (int qg = 0; qg < 2; qg++)
#pragma unroll
                for (int r = 0; r < 4; r++)
                    accO[dt][qg][r] += Cmb[qpair][lane][(dt * 2 + qg) * 4 + r];
        lsum[0] += Clsum[qpair][lane][0];
        lsum[1] += Clsum[qpair][lane][1];
        float inv[2];
#pragma unroll
        for (int qg = 0; qg < 2; qg++) {
            float l = lsum[qg];
            l += __shfl_xor(l, 16);
            l += __shfl_xor(l, 32);
            inv[qg] = 1.0f / l;
        }
        if constexpr (STAGE == 0) {
            u16* O = (u16*)outp;
            size_t rowb = (size_t)(b * N_ + qc * 64 + qpair * 32 + l16);
#pragma unroll
            for (int qg = 0; qg < 2; qg++)
#pragma unroll
                for (int dt = 0; dt < 4; dt++) {
                    ushort4 o;
                    o.x = f2bf(accO[dt][qg][0] * inv[qg]);
                    o.y = f2bf(accO[dt][qg][1] * inv[qg]);
                    o.z = f2bf(accO[dt][qg][2] * inv[qg]);
                    o.w = f2bf(accO[dt][qg][3] * inv[qg]);
                    *reinterpret_cast<ushort4*>(
                        &O[(rowb + qg * 16) * ostr + h * 64 + dt * 16 + g * 4]) = o;
                }
        }
    }
    if constexpr (STAGE == 1) {
        __shared__ float Os[64][68];
        if (kvh == 0) {
            float inv[2];
#pragma unroll
            for (int qg = 0; qg < 2; qg++) {
                float l = lsum[qg];
                l += __shfl_xor(l, 16);
                l += __shfl_xor(l, 32);
                inv[qg] = 1.0f / l;
            }
            int qrl = qpair * 32 + l16;
#pragma unroll
            for (int qg = 0; qg < 2; qg++)
#pragma unroll
                for (int dt = 0; dt < 4; dt++)
#pragma unroll
                    for (int r = 0; r < 4; r++)
                        Os[qrl + qg * 16][dt * 16 + g * 4 + r] = accO[dt][qg][r] * inv[qg];
        }
        __syncthreads();
        // batch-mixing scatter: n = qc*64+row; bo=(n&1)*8+h*2+(b>>3),
        // co=((n>>1)&3)*64+d, no=(b&7)*128+(n>>3); row = j*8 + (q2*2+tl)
        float* out = (float*)outp;
#pragma unroll
        for (int e = 0; e < 2; e++) {
            int seg = t + e * 256;          // 512 segs = 64 d x 8 (tl,q2)
            int d = seg & 63, tb = seg >> 6;
            int tl = tb & 1, q2 = (tb >> 1) & 3;
            int bo = tl * 8 + h * 2 + (b >> 3);
            int co = q2 * 64 + d;
            size_t base = (size_t)bo * (C_ * N_) + (size_t)co * N_ + (b & 7) * 128 + qc * 8;
            float4 v0, v1;
            v0.x = Os[0 * 8 + q2 * 2 + tl][d];
            v0.y = Os[1 * 8 + q2 * 2 + tl][d];
            v0.z = Os[2 * 8 + q2 * 2 + tl][d];
            v0.w = Os[3 * 8 + q2 * 2 + tl][d];
            v1.x = Os[4 * 8 + q2 * 2 + tl][d];
            v1.y = Os[5 * 8 + q2 * 2 + tl][d];
            v1.z = Os[6 * 8 + q2 * 2 + tl][d];
            v1.w = Os[7 * 8 + q2 * 2 + tl][d];
            *reinterpret_cast<float4*>(&out[base]) = v0;
            *reinterpret_cast<float4*>(&out[base + 4]) = v1;
        }
    }
}

extern "C" void kernel_launch(void* const* d_in, const int* in_sizes, int n_in,
                              void* d_out, int out_size, void* d_ws, size_t ws_size,
                              hipStream_t stream) {
    const float* x      = (const float*)d_in[0];
    const float* q_w    = (const float*)d_in[1];
    const float* kv_w   = (const float*)d_in[2];
    const float* proj_w = (const float*)d_in[3];
    const float* proj_b = (const float*)d_in[4];
    const float* lq_w   = (const float*)d_in[5];
    const float* lq_b   = (const float*)d_in[6];
    const float* lkv_w  = (const float*)d_in[7];
    const float* lkv_b  = (const float*)d_in[8];
    // d_in[9] = rel_bias: constant along softmax axis -> exact no-op
    const float* dw_w   = (const float*)d_in[10];
    const float* dw_b   = (const float*)d_in[11];

    const size_t SZ = (size_t)B_ * N_ * C_;  // 4M elems
    u16* ws = (u16*)d_ws;
    u16* xf    = ws;              // [0,SZ): xf, later s2in
    u16* qkv   = ws + SZ;         // [SZ,5SZ): ldc=1024: q | K | V | q2 columns
    u16* Kpk   = ws + 5 * SZ;     // [5SZ,6SZ): packed K, also ypb between stages
    u16* Vpk   = ws + 6 * SZ;     // [6SZ,7SZ): packed V
    u16* arena = ws + 7 * SZ;     // weights: wq|wkv|wlq|wproj|wlkv
    u16* wmega  = arena;          // wq|wkv|wlq stacked: [1024][256]
    u16* wproj  = arena + 262144;
    u16* wlkv   = arena + 327680;
    float* wT   = (float*)(arena + 458752);  // [9][256] f32 transposed dw weights
    u16* yb     = qkv + 256;      // attn0 out in dead K columns (stride 1024)
    u16* ypb    = Kpk;            // proj out in dead packed-K slot
    u16* s2in   = xf;             // conv+res out in dead xf slot

    k_f2bf5<<<449, 256, 0, stream>>>(q_w, kv_w, lq_w, proj_w, lkv_w, arena, dw_w, wT);
    k_transpose_x<<<dim3(32, 8, B_), dim3(32, 8), 0, stream>>>(x, xf);
    // mega GEMM: q | K | V | q2 (plain stores; bias lq_b on cols >= 768)
    k_gemm_bf16<<<dim3(8, 128), 256, 0, stream>>>(xf, 256, wmega, lq_b, 768,
                                                  qkv, 1024, 1024);
    k_packK<<<2048, 256, 0, stream>>>(qkv + 256, 1024, Kpk);
    k_packV<<<dim3(32, 8, B_), dim3(32, 8), 0, stream>>>(qkv + 512, 1024, Vpk);
    k_attn_mfma<0><<<1024, 256, 0, stream>>>(qkv, 1024, Kpk, Vpk, yb, 1024);
    k_gemm_bf16<<<dim3(2, 128), 256, 0, stream>>>(yb, 1024, wproj, proj_b, 0,
                                                  ypb, 256, 256);
    k_dwconv_add<<<dim3(128, B_), 256, 0, stream>>>(ypb, wT, dw_b, s2in);
    k_gemm_bf16<<<dim3(4, 128), 256, 0, stream>>>(s2in, 256, wlkv, lkv_b, 0,
                                                  qkv + 256, 512, 1024);
    k_packK<<<2048, 256, 0, stream>>>(qkv + 256, 1024, Kpk);
    k_packV<<<dim3(32, 8, B_), dim3(32, 8), 0, stream>>>(qkv + 512, 1024, Vpk);
    k_attn_mfma<1><<<1024, 256, 0, stream>>>(qkv + 768, 1024, Kpk, Vpk, d_out, 0);
}

// Round 17
// 136.725 us; speedup vs baseline: 6.4623x; 1.0572x over previous
//
#include <hip/hip_runtime.h>
#include <hip/hip_bf16.h>

#define B_  16
#define C_  256
#define N_  1024
#define H_  4

typedef unsigned short u16;
typedef __attribute__((ext_vector_type(8))) short bf16x8;
typedef __attribute__((ext_vector_type(4))) float f32x4;

#if __has_builtin(__builtin_amdgcn_exp2f)
#define EXP2(x) __builtin_amdgcn_exp2f(x)
#else
#define EXP2(x) __builtin_exp2f(x)
#endif

__device__ __forceinline__ u16 f2bf(float f) {
    union { float f; unsigned u; } v; v.f = f;
    unsigned r = v.u + 0x7FFFu + ((v.u >> 16) & 1u);
    return (u16)(r >> 16);
}
__device__ __forceinline__ float bf2f(u16 h) {
    union { unsigned u; float f; } v; v.u = ((unsigned)h) << 16;
    return v.f;
}
__device__ __forceinline__ unsigned pack2bf(float a, float b) {
    __hip_bfloat162 h = __float22bfloat162_rn(make_float2(a, b));
    union { __hip_bfloat162 h2; unsigned u; } cv; cv.h2 = h;
    return cv.u;
}
// async global->LDS, 16B per lane; lds base must be wave-uniform
__device__ __forceinline__ void gl_lds16(const u16* g, u16* l) {
    __builtin_amdgcn_global_load_lds(
        (const __attribute__((address_space(1))) void*)g,
        (__attribute__((address_space(3))) void*)l, 16, 0, 0);
}

// ---- prep: weights f32->bf16 arena + dw transpose + x transpose, one dispatch ----
// blocks [0,448): f2bf arena; 448: dw transpose; [449, 449+4096): x transpose
__global__ __launch_bounds__(256) void k_prep(const float* __restrict__ a0,
                                              const float* __restrict__ a1,
                                              const float* __restrict__ a2,
                                              const float* __restrict__ a3,
                                              const float* __restrict__ a4,
                                              u16* __restrict__ dst,
                                              const float* __restrict__ dw_w,
                                              float* __restrict__ wT,
                                              const float* __restrict__ x,
                                              u16* __restrict__ xf) {
    int blk = blockIdx.x;
    int t = threadIdx.x;
    if (blk < 448) {
        int i = blk * 256 + t;  // float4 index, total 114688
        const float* s; int off;
        if (i < 16384)      { s = a0; off = 0; }
        else if (i < 49152) { s = a1; off = 16384; }
        else if (i < 65536) { s = a2; off = 49152; }
        else if (i < 81920) { s = a3; off = 65536; }
        else                { s = a4; off = 81920; }
        float4 v = reinterpret_cast<const float4*>(s)[i - off];
        ushort4 o;
        o.x = f2bf(v.x); o.y = f2bf(v.y); o.z = f2bf(v.z); o.w = f2bf(v.w);
        reinterpret_cast<ushort4*>(dst)[i] = o;
    } else if (blk == 448) {
#pragma unroll
        for (int tap = 0; tap < 9; tap++)
            wT[tap * 256 + t] = dw_w[t * 9 + tap];
    } else {
        __shared__ u16 tile[32][33];
        int f = blk - 449;              // 4096 blocks: bx 32, by 8, bz 16
        int bx = f & 31, by = (f >> 5) & 7, b = f >> 8;
        int n0 = bx * 32, c0 = by * 32;
        int tx = t & 31, ty = t >> 5;   // 32 x 8
#pragma unroll
        for (int i = 0; i < 4; i++)
            tile[ty + i * 8][tx] =
                f2bf(x[((size_t)(b * C_ + c0 + ty + i * 8)) * N_ + n0 + tx]);
        __syncthreads();
#pragma unroll
        for (int i = 0; i < 4; i++)
            xf[((size_t)(b * N_ + n0 + ty + i * 8)) * C_ + c0 + tx] = tile[tx][ty + i * 8];
    }
}

// ---- pack K and V^T into MFMA-fragment chunk order, one dispatch ----
// blocks [0,2048): K pack (rperm baked in, coalesced 16B ld/st)
// blocks [2048,6144): V transpose-pack via LDS tile
__global__ __launch_bounds__(256) void k_packKV(const u16* __restrict__ src, int stride,
                                                u16* __restrict__ Kpk,
                                                u16* __restrict__ Vpk) {
    int blk = blockIdx.x;
    int t = threadIdx.x;
    if (blk < 2048) {
        const u16* Ksrc = src;  // K at col 0 of src region
        int tid = blk * 256 + t;
        int lane = tid & 63;
        int chunk = tid >> 6;
        int c = chunk & 7;
        int kb = (chunk >> 3) & 15;
        int bh = chunk >> 7;
        int h = bh & 3, b = bh >> 2;
        int nt = c >> 1, w2 = c & 1;
        int l16 = lane & 15, g = lane >> 4;
        int rn = kb * 64 + (nt >> 1) * 32 + (nt & 1) * 4 + (((l16 & 12) << 1) | (l16 & 3));
        const u16* sp = Ksrc + (size_t)(b * N_ + rn) * stride + h * 64 + w2 * 32 + g * 8;
        *reinterpret_cast<bf16x8*>(&Kpk[(size_t)chunk * 512 + lane * 8]) =
            *reinterpret_cast<const bf16x8*>(sp);
    } else {
        __shared__ u16 tile[32][33];
        int f = blk - 2048;             // bx 32, by 8, bz 16
        int bx = f & 31, by = (f >> 5) & 7, b = f >> 8;
        int n0 = bx * 32, vc0 = by * 32;
        int h = vc0 >> 6, dl = vc0 & 63;
        int bh = b * 4 + h;
        int kb = n0 >> 6, kc = (n0 >> 5) & 1;
        int tx = t & 31, ty = t >> 5;
        const u16* Vsrc = src + 256;    // V at col 256 of src region
#pragma unroll
        for (int i = 0; i < 4; i++)
            tile[ty + i * 8][tx] =
                Vsrc[(size_t)(b * N_ + n0 + ty + i * 8) * stride + vc0 + tx];
        __syncthreads();
        int g = (tx >> 3) & 3, j = tx & 7;
#pragma unroll
        for (int i = 0; i < 4; i++) {
            int cl = ty + i * 8;        // d-local 0..31
            int d = dl + cl;
            int dt = d >> 4;
            int lane = (d & 15) + 16 * g;
            size_t addr = ((size_t)(bh * 16 + kb) * 8 + kc * 4 + dt) * 512 + lane * 8 + j;
            Vpk[addr] = tile[tx][cl];
        }
    }
}

// -------- MFMA GEMM (m97-style): linear LDS + global_load_lds width-16 --------
// A rows stride astr, C rows stride ldc. Tile 128x128, BK=32, 4 waves.
// bias applies to cols n >= bofs as bias[n-bofs].
__global__ __launch_bounds__(256) void k_gemm_bf16(const u16* __restrict__ A, int astr,
                                                   const u16* __restrict__ W,
                                                   const float* __restrict__ bias,
                                                   int bofs, u16* __restrict__ C,
                                                   int Nout, int ldc) {
    __shared__ u16 As[128 * 32];
    __shared__ u16 Bs[128 * 32];
    int m0 = blockIdx.y * 128, n0 = blockIdx.x * 128;
    int t = threadIdx.x;
    int wid = t >> 6, lane = t & 63;
    int l16 = lane & 15, g = lane >> 4;
    int wm = (wid >> 1) * 64, wn = (wid & 1) * 64;
    int srow0 = (lane >> 2);
    int scol = (lane & 3) * 8;
    f32x4 zz = {0.f, 0.f, 0.f, 0.f};
    f32x4 acc[4][4];
#pragma unroll
    for (int i = 0; i < 4; i++)
#pragma unroll
        for (int j = 0; j < 4; j++) acc[i][j] = zz;
    for (int k0 = 0; k0 < 256; k0 += 32) {
        __syncthreads();
#pragma unroll
        for (int i = 0; i < 2; i++) {
            int rr = (wid * 2 + i) * 16;
            gl_lds16(A + (size_t)(m0 + rr + srow0) * astr + k0 + scol, &As[rr * 32]);
            gl_lds16(W + (size_t)(n0 + rr + srow0) * 256 + k0 + scol, &Bs[rr * 32]);
        }
        __syncthreads();
        bf16x8 af[4], bfr[4];
#pragma unroll
        for (int mt = 0; mt < 4; mt++)
            af[mt] = *reinterpret_cast<const bf16x8*>(&As[(wm + mt * 16 + l16) * 32 + g * 8]);
#pragma unroll
        for (int nt = 0; nt < 4; nt++)
            bfr[nt] = *reinterpret_cast<const bf16x8*>(&Bs[(wn + nt * 16 + l16) * 32 + g * 8]);
#pragma unroll
        for (int mt = 0; mt < 4; mt++)
#pragma unroll
            for (int nt = 0; nt < 4; nt++)
                acc[mt][nt] = __builtin_amdgcn_mfma_f32_16x16x32_bf16(
                    af[mt], bfr[nt], acc[mt][nt], 0, 0, 0);
    }
    float bval[4];
#pragma unroll
    for (int nt = 0; nt < 4; nt++) {
        int n = n0 + wn + nt * 16 + l16;
        bval[nt] = (bias && n >= bofs) ? bias[n - bofs] : 0.0f;
    }
#pragma unroll
    for (int mt = 0; mt < 4; mt++)
#pragma unroll
        for (int r = 0; r < 4; r++) {
            int m = m0 + wm + mt * 16 + g * 4 + r;
#pragma unroll
            for (int nt = 0; nt < 4; nt++) {
                int n = n0 + wn + nt * 16 + l16;
                C[(size_t)m * ldc + n] = f2bf(acc[mt][nt][r] + bval[nt]);
            }
        }
}

// ------- depthwise 3x3 conv + bias + residual, vectorized (short8/lane) -------
__global__ __launch_bounds__(256) void k_dwconv_add(const u16* __restrict__ yp,
                                                    const float* __restrict__ wT,
                                                    const float* __restrict__ dw_b,
                                                    u16* __restrict__ out) {
    int b = blockIdx.y;
    int px = blockIdx.x * 8 + (threadIdx.x >> 5);
    int cc0 = (threadIdx.x & 31) * 8;
    int yy = px >> 5, xx = px & 31;
    const u16* ypb = yp + (size_t)b * N_ * C_;
    float acc[8];
    {
        float4 b0 = *reinterpret_cast<const float4*>(&dw_b[cc0]);
        float4 b1 = *reinterpret_cast<const float4*>(&dw_b[cc0 + 4]);
        acc[0] = b0.x; acc[1] = b0.y; acc[2] = b0.z; acc[3] = b0.w;
        acc[4] = b1.x; acc[5] = b1.y; acc[6] = b1.z; acc[7] = b1.w;
    }
#pragma unroll
    for (int dy = 0; dy < 3; dy++) {
        int y2 = yy + dy - 1;
        if (y2 < 0 || y2 >= 32) continue;
#pragma unroll
        for (int dx = 0; dx < 3; dx++) {
            int x2 = xx + dx - 1;
            if (x2 < 0 || x2 >= 32) continue;
            int tap = dy * 3 + dx;
            bf16x8 v = *reinterpret_cast<const bf16x8*>(
                &ypb[(size_t)(y2 * 32 + x2) * C_ + cc0]);
            float4 w0 = *reinterpret_cast<const float4*>(&wT[tap * 256 + cc0]);
            float4 w1 = *reinterpret_cast<const float4*>(&wT[tap * 256 + cc0 + 4]);
            acc[0] += bf2f((u16)v[0]) * w0.x;
            acc[1] += bf2f((u16)v[1]) * w0.y;
            acc[2] += bf2f((u16)v[2]) * w0.z;
            acc[3] += bf2f((u16)v[3]) * w0.w;
            acc[4] += bf2f((u16)v[4]) * w1.x;
            acc[5] += bf2f((u16)v[5]) * w1.y;
            acc[6] += bf2f((u16)v[6]) * w1.z;
            acc[7] += bf2f((u16)v[7]) * w1.w;
        }
    }
    bf16x8 ctr = *reinterpret_cast<const bf16x8*>(&ypb[(size_t)px * C_ + cc0]);
    bf16x8 o;
#pragma unroll
    for (int j = 0; j < 8; j++)
        o[j] = (short)f2bf(acc[j] + bf2f((u16)ctr[j]));
    *reinterpret_cast<bf16x8*>(&out[((size_t)b * N_ + px) * C_ + cc0]) = o;
}

// ---------------- MFMA flash attention: all-register P, packed K/V ------------
// R13-proven structure: block = 4 waves over 64 q-rows, wave (qpair, kvh) does
// 32 q-rows x 8 kv tiles; 2-way kv-split partials combine via LDS. Grid 1024.
// No setprio (R11/R12 lesson); launch_bounds (256,4) (R14/R15 spill lesson).
template <int STAGE>
__global__ __launch_bounds__(256, 4) void k_attn_mfma(const u16* __restrict__ Q, int qstr,
                                                      const u16* __restrict__ Kpk,
                                                      const u16* __restrict__ Vpk,
                                                      void* __restrict__ outp, int ostr) {
    __shared__ float Cmb[2][64][33];
    __shared__ float Clsum[2][64][2];
    int cid = blockIdx.x;
    int xcd = cid & 7, slot = cid >> 3;  // slot in [0,128)
    int bh = xcd * 8 + (slot & 7);       // 64 (b,h) panels, 8 per XCD
    int qc = slot >> 3;                  // q-chunk 0..15 (64 rows each)
    int h = bh & 3, b = bh >> 2;
    int t = threadIdx.x;
    int wv = t >> 6, lane = t & 63;
    int qpair = wv >> 1, kvh = wv & 1;
    int l16 = lane & 15, g = lane >> 4, g8 = g * 8;

    const float SCL = 0.18033688011112042f;  // 0.125*log2(e)
    const u16* Qb =
        Q + ((size_t)(b * N_ + qc * 64 + qpair * 32 + l16)) * qstr + h * 64 + g8;
    bf16x8 qf[2][2];
#pragma unroll
    for (int qg = 0; qg < 2; qg++)
#pragma unroll
        for (int w2 = 0; w2 < 2; w2++) {
            qf[qg][w2] = *reinterpret_cast<const bf16x8*>(Qb + qg * 16 * qstr + w2 * 32);
#pragma unroll
            for (int j = 0; j < 8; j++)
                qf[qg][w2][j] = (short)f2bf(bf2f((u16)qf[qg][w2][j]) * SCL);
        }

    const u16* Kp = Kpk + (size_t)bh * 65536 + lane * 8;
    const u16* Vp = Vpk + (size_t)bh * 65536 + lane * 8;

    int kb0 = kvh * 8, kb1 = kb0 + 8;
    bf16x8 kf[4][2];
#pragma unroll
    for (int nt = 0; nt < 4; nt++)
#pragma unroll
        for (int w2 = 0; w2 < 2; w2++)
            kf[nt][w2] = *reinterpret_cast<const bf16x8*>(
                Kp + (size_t)(kb0 * 8 + nt * 2 + w2) * 512);

    f32x4 zz = {0.f, 0.f, 0.f, 0.f};
    f32x4 accO[4][2];
#pragma unroll
    for (int dt = 0; dt < 4; dt++)
#pragma unroll
        for (int qg = 0; qg < 2; qg++) accO[dt][qg] = zz;
    float lsum[2] = {0.f, 0.f};
    int pwv[2][8];

    for (int kb = kb0; kb < kb1; kb++) {
        bf16x8 vf[2][4];
#pragma unroll
        for (int kc = 0; kc < 2; kc++)
#pragma unroll
            for (int dt = 0; dt < 4; dt++)
                vf[kc][dt] = *reinterpret_cast<const bf16x8*>(
                    Vp + (size_t)(kb * 8 + kc * 4 + dt) * 512);
#pragma unroll
        for (int qg = 0; qg < 2; qg++) {
            f32x4 st[4];
#pragma unroll
            for (int nt = 0; nt < 4; nt++) st[nt] = zz;
#pragma unroll
            for (int nt = 0; nt < 4; nt++) {
                st[nt] = __builtin_amdgcn_mfma_f32_16x16x32_bf16(kf[nt][0], qf[qg][0],
                                                                 st[nt], 0, 0, 0);
                st[nt] = __builtin_amdgcn_mfma_f32_16x16x32_bf16(kf[nt][1], qf[qg][1],
                                                                 st[nt], 0, 0, 0);
            }
#pragma unroll
            for (int nt = 0; nt < 4; nt++) {
                float p0 = EXP2(st[nt][0]);
                float p1 = EXP2(st[nt][1]);
                float p2 = EXP2(st[nt][2]);
                float p3 = EXP2(st[nt][3]);
                lsum[qg] += (p0 + p1) + (p2 + p3);
                pwv[qg][nt * 2 + 0] = (int)pack2bf(p0, p1);
                pwv[qg][nt * 2 + 1] = (int)pack2bf(p2, p3);
            }
        }
        {
            int nkb = (kb < kb1 - 1) ? kb + 1 : kb;
#pragma unroll
            for (int nt = 0; nt < 4; nt++)
#pragma unroll
                for (int w2 = 0; w2 < 2; w2++)
                    kf[nt][w2] = *reinterpret_cast<const bf16x8*>(
                        Kp + (size_t)(nkb * 8 + nt * 2 + w2) * 512);
        }
#pragma unroll
        for (int qg = 0; qg < 2; qg++)
#pragma unroll
            for (int kc = 0; kc < 2; kc++) {
                union { int i[4]; bf16x8 v; } u;
                u.i[0] = pwv[qg][4 * kc + 0];
                u.i[1] = pwv[qg][4 * kc + 1];
                u.i[2] = pwv[qg][4 * kc + 2];
                u.i[3] = pwv[qg][4 * kc + 3];
#pragma unroll
                for (int dt = 0; dt < 4; dt++)
                    accO[dt][qg] = __builtin_amdgcn_mfma_f32_16x16x32_bf16(
                        vf[kc][dt], u.v, accO[dt][qg], 0, 0, 0);
            }
    }

    if (kvh == 1) {
#pragma unroll
        for (int dt = 0; dt < 4; dt++)
#pragma unroll
            for (int qg = 0; qg < 2; qg++)
#pragma unroll
                for (int r = 0; r < 4; r++)
                    Cmb[qpair][lane][(dt * 2 + qg) * 4 + r] = accO[dt][qg][r];
        Clsum[qpair][lane][0] = lsum[0];
        Clsum[qpair][lane][1] = lsum[1];
    }
    __syncthreads();
    if (kvh == 0) {
#pragma unroll
        for (int dt = 0; dt < 4; dt++)
#pragma unroll
            for (int qg = 0; qg < 2; qg++)
#pragma unroll
                for (int r = 0; r < 4; r++)
                    accO[dt][qg][r] += Cmb[qpair][lane][(dt * 2 + qg) * 4 + r];
        lsum[0] += Clsum[qpair][lane][0];
        lsum[1] += Clsum[qpair][lane][1];
        float inv[2];
#pragma unroll
        for (int qg = 0; qg < 2; qg++) {
            float l = lsum[qg];
            l += __shfl_xor(l, 16);
            l += __shfl_xor(l, 32);
            inv[qg] = 1.0f / l;
        }
        if constexpr (STAGE == 0) {
            u16* O = (u16*)outp;
            size_t rowb = (size_t)(b * N_ + qc * 64 + qpair * 32 + l16);
#pragma unroll
            for (int qg = 0; qg < 2; qg++)
#pragma unroll
                for (int dt = 0; dt < 4; dt++) {
                    ushort4 o;
                    o.x = f2bf(accO[dt][qg][0] * inv[qg]);
                    o.y = f2bf(accO[dt][qg][1] * inv[qg]);
                    o.z = f2bf(accO[dt][qg][2] * inv[qg]);
                    o.w = f2bf(accO[dt][qg][3] * inv[qg]);
                    *reinterpret_cast<ushort4*>(
                        &O[(rowb + qg * 16) * ostr + h * 64 + dt * 16 + g * 4]) = o;
                }
        }
    }
    if constexpr (STAGE == 1) {
        __shared__ float Os[64][68];
        if (kvh == 0) {
            float inv[2];
#pragma unroll
            for (int qg = 0; qg < 2; qg++) {
                float l = lsum[qg];
                l += __shfl_xor(l, 16);
                l += __shfl_xor(l, 32);
                inv[qg] = 1.0f / l;
            }
            int qrl = qpair * 32 + l16;
#pragma unroll
            for (int qg = 0; qg < 2; qg++)
#pragma unroll
                for (int dt = 0; dt < 4; dt++)
#pragma unroll
                    for (int r = 0; r < 4; r++)
                        Os[qrl + qg * 16][dt * 16 + g * 4 + r] = accO[dt][qg][r] * inv[qg];
        }
        __syncthreads();
        // batch-mixing scatter: n = qc*64+row; bo=(n&1)*8+h*2+(b>>3),
        // co=((n>>1)&3)*64+d, no=(b&7)*128+(n>>3); row = j*8 + (q2*2+tl)
        float* out = (float*)outp;
#pragma unroll
        for (int e = 0; e < 2; e++) {
            int seg = t + e * 256;          // 512 segs = 64 d x 8 (tl,q2)
            int d = seg & 63, tb = seg >> 6;
            int tl = tb & 1, q2 = (tb >> 1) & 3;
            int bo = tl * 8 + h * 2 + (b >> 3);
            int co = q2 * 64 + d;
            size_t base = (size_t)bo * (C_ * N_) + (size_t)co * N_ + (b & 7) * 128 + qc * 8;
            float4 v0, v1;
            v0.x = Os[0 * 8 + q2 * 2 + tl][d];
            v0.y = Os[1 * 8 + q2 * 2 + tl][d];
            v0.z = Os[2 * 8 + q2 * 2 + tl][d];
            v0.w = Os[3 * 8 + q2 * 2 + tl][d];
            v1.x = Os[4 * 8 + q2 * 2 + tl][d];
            v1.y = Os[5 * 8 + q2 * 2 + tl][d];
            v1.z = Os[6 * 8 + q2 * 2 + tl][d];
            v1.w = Os[7 * 8 + q2 * 2 + tl][d];
            *reinterpret_cast<float4*>(&out[base]) = v0;
            *reinterpret_cast<float4*>(&out[base + 4]) = v1;
        }
    }
}

extern "C" void kernel_launch(void* const* d_in, const int* in_sizes, int n_in,
                              void* d_out, int out_size, void* d_ws, size_t ws_size,
                              hipStream_t stream) {
    const float* x      = (const float*)d_in[0];
    const float* q_w    = (const float*)d_in[1];
    const float* kv_w   = (const float*)d_in[2];
    const float* proj_w = (const float*)d_in[3];
    const float* proj_b = (const float*)d_in[4];
    const float* lq_w   = (const float*)d_in[5];
    const float* lq_b   = (const float*)d_in[6];
    const float* lkv_w  = (const float*)d_in[7];
    const float* lkv_b  = (const float*)d_in[8];
    // d_in[9] = rel_bias: constant along softmax axis -> exact no-op
    const float* dw_w   = (const float*)d_in[10];
    const float* dw_b   = (const float*)d_in[11];

    const size_t SZ = (size_t)B_ * N_ * C_;  // 4M elems
    u16* ws = (u16*)d_ws;
    u16* xf    = ws;              // [0,SZ): xf, later s2in
    u16* qkv   = ws + SZ;         // [SZ,5SZ): ldc=1024: q | K | V | q2 columns
    u16* Kpk   = ws + 5 * SZ;     // [5SZ,6SZ): packed K, also ypb between stages
    u16* Vpk   = ws + 6 * SZ;     // [6SZ,7SZ): packed V
    u16* arena = ws + 7 * SZ;     // weights: wq|wkv|wlq|wproj|wlkv
    u16* wmega  = arena;          // wq|wkv|wlq stacked: [1024][256]
    u16* wproj  = arena + 262144;
    u16* wlkv   = arena + 327680;
    float* wT   = (float*)(arena + 458752);  // [9][256] f32 transposed dw weights
    u16* yb     = qkv + 256;      // attn0 out in dead K columns (stride 1024)
    u16* ypb    = Kpk;            // proj out in dead packed-K slot
    u16* s2in   = xf;             // conv+res out in dead xf slot

    k_prep<<<4545, 256, 0, stream>>>(q_w, kv_w, lq_w, proj_w, lkv_w, arena,
                                     dw_w, wT, x, xf);
    // mega GEMM: q | K | V | q2 (plain stores; bias lq_b on cols >= 768)
    k_gemm_bf16<<<dim3(8, 128), 256, 0, stream>>>(xf, 256, wmega, lq_b, 768,
                                                  qkv, 1024, 1024);
    k_packKV<<<6144, 256, 0, stream>>>(qkv + 256, 1024, Kpk, Vpk);
    k_attn_mfma<0><<<1024, 256, 0, stream>>>(qkv, 1024, Kpk, Vpk, yb, 1024);
    k_gemm_bf16<<<dim3(2, 128), 256, 0, stream>>>(yb, 1024, wproj, proj_b, 0,
                                                  ypb, 256, 256);
    k_dwconv_add<<<dim3(128, B_), 256, 0, stream>>>(ypb, wT, dw_b, s2in);
    k_gemm_bf16<<<dim3(4, 128), 256, 0, stream>>>(s2in, 256, wlkv, lkv_b, 0,
                                                  qkv + 256, 512, 1024);
    k_packKV<<<6144, 256, 0, stream>>>(qkv + 256, 1024, Kpk, Vpk);
    k_attn_mfma<1><<<1024, 256, 0, stream>>>(qkv + 768, 1024, Kpk, Vpk, d_out, 0);
}

// Round 18
// 130.079 us; speedup vs baseline: 6.7925x; 1.0511x over previous
//
#include <hip/hip_runtime.h>
#include <hip/hip_bf16.h>

#define B_  16
#define C_  256
#define N_  1024
#define H_  4

typedef unsigned short u16;
typedef __attribute__((ext_vector_type(8))) short bf16x8;
typedef __attribute__((ext_vector_type(4))) float f32x4;

#if __has_builtin(__builtin_amdgcn_exp2f)
#define EXP2(x) __builtin_amdgcn_exp2f(x)
#else
#define EXP2(x) __builtin_exp2f(x)
#endif

__device__ __forceinline__ u16 f2bf(float f) {
    union { float f; unsigned u; } v; v.f = f;
    unsigned r = v.u + 0x7FFFu + ((v.u >> 16) & 1u);
    return (u16)(r >> 16);
}
__device__ __forceinline__ float bf2f(u16 h) {
    union { unsigned u; float f; } v; v.u = ((unsigned)h) << 16;
    return v.f;
}
__device__ __forceinline__ unsigned pack2bf(float a, float b) {
    __hip_bfloat162 h = __float22bfloat162_rn(make_float2(a, b));
    union { __hip_bfloat162 h2; unsigned u; } cv; cv.h2 = h;
    return cv.u;
}
// async global->LDS, 16B per lane; lds base must be wave-uniform
__device__ __forceinline__ void gl_lds16(const u16* g, u16* l) {
    __builtin_amdgcn_global_load_lds(
        (const __attribute__((address_space(1))) void*)g,
        (__attribute__((address_space(3))) void*)l, 16, 0, 0);
}

// ---- prep: weights f32->bf16 arena + dw transpose + x transpose, one dispatch ----
// blocks [0,448): f2bf arena; 448: dw transpose; [449, 449+4096): x transpose
__global__ __launch_bounds__(256) void k_prep(const float* __restrict__ a0,
                                              const float* __restrict__ a1,
                                              const float* __restrict__ a2,
                                              const float* __restrict__ a3,
                                              const float* __restrict__ a4,
                                              u16* __restrict__ dst,
                                              const float* __restrict__ dw_w,
                                              float* __restrict__ wT,
                                              const float* __restrict__ x,
                                              u16* __restrict__ xf) {
    int blk = blockIdx.x;
    int t = threadIdx.x;
    if (blk < 448) {
        int i = blk * 256 + t;  // float4 index, total 114688
        const float* s; int off;
        if (i < 16384)      { s = a0; off = 0; }
        else if (i < 49152) { s = a1; off = 16384; }
        else if (i < 65536) { s = a2; off = 49152; }
        else if (i < 81920) { s = a3; off = 65536; }
        else                { s = a4; off = 81920; }
        float4 v = reinterpret_cast<const float4*>(s)[i - off];
        ushort4 o;
        o.x = f2bf(v.x); o.y = f2bf(v.y); o.z = f2bf(v.z); o.w = f2bf(v.w);
        reinterpret_cast<ushort4*>(dst)[i] = o;
    } else if (blk == 448) {
#pragma unroll
        for (int tap = 0; tap < 9; tap++)
            wT[tap * 256 + t] = dw_w[t * 9 + tap];
    } else {
        __shared__ u16 tile[32][33];
        int f = blk - 449;              // 4096 blocks: bx 32, by 8, bz 16
        int bx = f & 31, by = (f >> 5) & 7, b = f >> 8;
        int n0 = bx * 32, c0 = by * 32;
        int tx = t & 31, ty = t >> 5;   // 32 x 8
#pragma unroll
        for (int i = 0; i < 4; i++)
            tile[ty + i * 8][tx] =
                f2bf(x[((size_t)(b * C_ + c0 + ty + i * 8)) * N_ + n0 + tx]);
        __syncthreads();
#pragma unroll
        for (int i = 0; i < 4; i++)
            xf[((size_t)(b * N_ + n0 + ty + i * 8)) * C_ + c0 + tx] = tile[tx][ty + i * 8];
    }
}

// -------- MFMA GEMM (m97-style) with pack-routing epilogue --------
// A rows stride astr, C rows stride ldc. Tile 128x128, BK=32, 4 waves.
// bias applies to cols n >= bofs as bias[n-bofs].
// Cols [kpk_lo, kpk_lo+256) -> packed-K store (k_packK layout, rperm baked in);
// cols [vpk_lo, vpk_lo+256) -> packed-V^T store (k_packV layout);
// other cols -> normal C store. (R11/R12 A/B: pack-fold epilogue is cost-
// neutral vs separate pack kernel; deletes the 32MB round trip + dispatch.)
__global__ __launch_bounds__(256) void k_gemm_bf16(const u16* __restrict__ A, int astr,
                                                   const u16* __restrict__ W,
                                                   const float* __restrict__ bias,
                                                   int bofs, u16* __restrict__ C,
                                                   int ldc,
                                                   u16* __restrict__ Kpk, int kpk_lo,
                                                   u16* __restrict__ Vpk, int vpk_lo) {
    __shared__ u16 As[128 * 32];
    __shared__ u16 Bs[128 * 32];
    int m0 = blockIdx.y * 128, n0 = blockIdx.x * 128;
    int t = threadIdx.x;
    int wid = t >> 6, lane = t & 63;
    int l16 = lane & 15, g = lane >> 4;
    int wm = (wid >> 1) * 64, wn = (wid & 1) * 64;
    int srow0 = (lane >> 2);
    int scol = (lane & 3) * 8;
    f32x4 zz = {0.f, 0.f, 0.f, 0.f};
    f32x4 acc[4][4];
#pragma unroll
    for (int i = 0; i < 4; i++)
#pragma unroll
        for (int j = 0; j < 4; j++) acc[i][j] = zz;
    for (int k0 = 0; k0 < 256; k0 += 32) {
        __syncthreads();
#pragma unroll
        for (int i = 0; i < 2; i++) {
            int rr = (wid * 2 + i) * 16;
            gl_lds16(A + (size_t)(m0 + rr + srow0) * astr + k0 + scol, &As[rr * 32]);
            gl_lds16(W + (size_t)(n0 + rr + srow0) * 256 + k0 + scol, &Bs[rr * 32]);
        }
        __syncthreads();
        bf16x8 af[4], bfr[4];
#pragma unroll
        for (int mt = 0; mt < 4; mt++)
            af[mt] = *reinterpret_cast<const bf16x8*>(&As[(wm + mt * 16 + l16) * 32 + g * 8]);
#pragma unroll
        for (int nt = 0; nt < 4; nt++)
            bfr[nt] = *reinterpret_cast<const bf16x8*>(&Bs[(wn + nt * 16 + l16) * 32 + g * 8]);
#pragma unroll
        for (int mt = 0; mt < 4; mt++)
#pragma unroll
            for (int nt = 0; nt < 4; nt++)
                acc[mt][nt] = __builtin_amdgcn_mfma_f32_16x16x32_bf16(
                    af[mt], bfr[nt], acc[mt][nt], 0, 0, 0);
    }
    float bval[4];
#pragma unroll
    for (int nt = 0; nt < 4; nt++) {
        int n = n0 + wn + nt * 16 + l16;
        bval[nt] = (bias && n >= bofs) ? bias[n - bofs] : 0.0f;
    }
    bool kpack = (n0 >= kpk_lo) && (n0 < kpk_lo + 256);
    bool vpack = (n0 >= vpk_lo) && (n0 < vpk_lo + 256);
    if (kpack) {
        int hcol = n0 - kpk_lo + wn;
#pragma unroll
        for (int mt = 0; mt < 4; mt++)
#pragma unroll
            for (int r = 0; r < 4; r++) {
                int m = m0 + wm + mt * 16 + g * 4 + r;
                int b = m >> 10, rn = m & 1023;
                int kb = rn >> 6, r6 = rn & 63;
                int nt2 = ((r6 >> 5) << 1) | ((r6 >> 2) & 1);
                int l2 = (r6 & 3) | ((r6 >> 1) & 12);
#pragma unroll
                for (int nt = 0; nt < 4; nt++) {
                    int c = hcol + nt * 16 + l16;
                    int h = c >> 6, c6 = c & 63;
                    int w2 = c6 >> 5, g2 = (c6 >> 3) & 3, j = c6 & 7;
                    size_t chunk = ((size_t)(b * 4 + h) * 16 + kb) * 8 + nt2 * 2 + w2;
                    Kpk[chunk * 512 + (l2 + 16 * g2) * 8 + j] =
                        f2bf(acc[mt][nt][r] + bval[nt]);
                }
            }
    } else if (vpack) {
        int hcol = n0 - vpk_lo + wn;
#pragma unroll
        for (int mt = 0; mt < 4; mt++)
#pragma unroll
            for (int r = 0; r < 4; r++) {
                int m = m0 + wm + mt * 16 + g * 4 + r;
                int b = m >> 10;
                int kv = m & 1023;
                int kb = kv >> 6;
                int kc = (kv >> 5) & 1;
                int g3 = (kv >> 3) & 3;
                int j = kv & 7;
#pragma unroll
                for (int nt = 0; nt < 4; nt++) {
                    int c = hcol + nt * 16 + l16;
                    int h = c >> 6, d6 = c & 63;
                    int dt = d6 >> 4, d15 = d6 & 15;
                    size_t chunk = ((size_t)(b * 4 + h) * 16 + kb) * 8 + kc * 4 + dt;
                    Vpk[chunk * 512 + (d15 + 16 * g3) * 8 + j] =
                        f2bf(acc[mt][nt][r] + bval[nt]);
                }
            }
    } else {
#pragma unroll
        for (int mt = 0; mt < 4; mt++)
#pragma unroll
            for (int r = 0; r < 4; r++) {
                int m = m0 + wm + mt * 16 + g * 4 + r;
#pragma unroll
                for (int nt = 0; nt < 4; nt++) {
                    int n = n0 + wn + nt * 16 + l16;
                    C[(size_t)m * ldc + n] = f2bf(acc[mt][nt][r] + bval[nt]);
                }
            }
    }
}

// ------- depthwise 3x3 conv + bias + residual, vectorized (short8/lane) -------
__global__ __launch_bounds__(256) void k_dwconv_add(const u16* __restrict__ yp,
                                                    const float* __restrict__ wT,
                                                    const float* __restrict__ dw_b,
                                                    u16* __restrict__ out) {
    int b = blockIdx.y;
    int px = blockIdx.x * 8 + (threadIdx.x >> 5);
    int cc0 = (threadIdx.x & 31) * 8;
    int yy = px >> 5, xx = px & 31;
    const u16* ypb = yp + (size_t)b * N_ * C_;
    float acc[8];
    {
        float4 b0 = *reinterpret_cast<const float4*>(&dw_b[cc0]);
        float4 b1 = *reinterpret_cast<const float4*>(&dw_b[cc0 + 4]);
        acc[0] = b0.x; acc[1] = b0.y; acc[2] = b0.z; acc[3] = b0.w;
        acc[4] = b1.x; acc[5] = b1.y; acc[6] = b1.z; acc[7] = b1.w;
    }
#pragma unroll
    for (int dy = 0; dy < 3; dy++) {
        int y2 = yy + dy - 1;
        if (y2 < 0 || y2 >= 32) continue;
#pragma unroll
        for (int dx = 0; dx < 3; dx++) {
            int x2 = xx + dx - 1;
            if (x2 < 0 || x2 >= 32) continue;
            int tap = dy * 3 + dx;
            bf16x8 v = *reinterpret_cast<const bf16x8*>(
                &ypb[(size_t)(y2 * 32 + x2) * C_ + cc0]);
            float4 w0 = *reinterpret_cast<const float4*>(&wT[tap * 256 + cc0]);
            float4 w1 = *reinterpret_cast<const float4*>(&wT[tap * 256 + cc0 + 4]);
            acc[0] += bf2f((u16)v[0]) * w0.x;
            acc[1] += bf2f((u16)v[1]) * w0.y;
            acc[2] += bf2f((u16)v[2]) * w0.z;
            acc[3] += bf2f((u16)v[3]) * w0.w;
            acc[4] += bf2f((u16)v[4]) * w1.x;
            acc[5] += bf2f((u16)v[5]) * w1.y;
            acc[6] += bf2f((u16)v[6]) * w1.z;
            acc[7] += bf2f((u16)v[7]) * w1.w;
        }
    }
    bf16x8 ctr = *reinterpret_cast<const bf16x8*>(&ypb[(size_t)px * C_ + cc0]);
    bf16x8 o;
#pragma unroll
    for (int j = 0; j < 8; j++)
        o[j] = (short)f2bf(acc[j] + bf2f((u16)ctr[j]));
    *reinterpret_cast<bf16x8*>(&out[((size_t)b * N_ + px) * C_ + cc0]) = o;
}

// ---------------- MFMA flash attention: all-register P, packed K/V ------------
// R13-proven structure: block = 4 waves over 64 q-rows, wave (qpair, kvh) does
// 32 q-rows x 8 kv tiles; 2-way kv-split partials combine via LDS. Grid 1024.
// No setprio (R11/R12 lesson); launch_bounds (256,4) (R14/R15 spill lesson).
template <int STAGE>
__global__ __launch_bounds__(256, 4) void k_attn_mfma(const u16* __restrict__ Q, int qstr,
                                                      const u16* __restrict__ Kpk,
                                                      const u16* __restrict__ Vpk,
                                                      void* __restrict__ outp, int ostr) {
    __shared__ float Cmb[2][64][33];
    __shared__ float Clsum[2][64][2];
    int cid = blockIdx.x;
    int xcd = cid & 7, slot = cid >> 3;  // slot in [0,128)
    int bh = xcd * 8 + (slot & 7);       // 64 (b,h) panels, 8 per XCD
    int qc = slot >> 3;                  // q-chunk 0..15 (64 rows each)
    int h = bh & 3, b = bh >> 2;
    int t = threadIdx.x;
    int wv = t >> 6, lane = t & 63;
    int qpair = wv >> 1, kvh = wv & 1;
    int l16 = lane & 15, g = lane >> 4, g8 = g * 8;

    const float SCL = 0.18033688011112042f;  // 0.125*log2(e)
    const u16* Qb =
        Q + ((size_t)(b * N_ + qc * 64 + qpair * 32 + l16)) * qstr + h * 64 + g8;
    bf16x8 qf[2][2];
#pragma unroll
    for (int qg = 0; qg < 2; qg++)
#pragma unroll
        for (int w2 = 0; w2 < 2; w2++) {
            qf[qg][w2] = *reinterpret_cast<const bf16x8*>(Qb + qg * 16 * qstr + w2 * 32);
#pragma unroll
            for (int j = 0; j < 8; j++)
                qf[qg][w2][j] = (short)f2bf(bf2f((u16)qf[qg][w2][j]) * SCL);
        }

    const u16* Kp = Kpk + (size_t)bh * 65536 + lane * 8;
    const u16* Vp = Vpk + (size_t)bh * 65536 + lane * 8;

    int kb0 = kvh * 8, kb1 = kb0 + 8;
    bf16x8 kf[4][2];
#pragma unroll
    for (int nt = 0; nt < 4; nt++)
#pragma unroll
        for (int w2 = 0; w2 < 2; w2++)
            kf[nt][w2] = *reinterpret_cast<const bf16x8*>(
                Kp + (size_t)(kb0 * 8 + nt * 2 + w2) * 512);

    f32x4 zz = {0.f, 0.f, 0.f, 0.f};
    f32x4 accO[4][2];
#pragma unroll
    for (int dt = 0; dt < 4; dt++)
#pragma unroll
        for (int qg = 0; qg < 2; qg++) accO[dt][qg] = zz;
    float lsum[2] = {0.f, 0.f};
    int pwv[2][8];

    for (int kb = kb0; kb < kb1; kb++) {
        bf16x8 vf[2][4];
#pragma unroll
        for (int kc = 0; kc < 2; kc++)
#pragma unroll
            for (int dt = 0; dt < 4; dt++)
                vf[kc][dt] = *reinterpret_cast<const bf16x8*>(
                    Vp + (size_t)(kb * 8 + kc * 4 + dt) * 512);
#pragma unroll
        for (int qg = 0; qg < 2; qg++) {
            f32x4 st[4];
#pragma unroll
            for (int nt = 0; nt < 4; nt++) st[nt] = zz;
#pragma unroll
            for (int nt = 0; nt < 4; nt++) {
                st[nt] = __builtin_amdgcn_mfma_f32_16x16x32_bf16(kf[nt][0], qf[qg][0],
                                                                 st[nt], 0, 0, 0);
                st[nt] = __builtin_amdgcn_mfma_f32_16x16x32_bf16(kf[nt][1], qf[qg][1],
                                                                 st[nt], 0, 0, 0);
            }
#pragma unroll
            for (int nt = 0; nt < 4; nt++) {
                float p0 = EXP2(st[nt][0]);
                float p1 = EXP2(st[nt][1]);
                float p2 = EXP2(st[nt][2]);
                float p3 = EXP2(st[nt][3]);
                lsum[qg] += (p0 + p1) + (p2 + p3);
                pwv[qg][nt * 2 + 0] = (int)pack2bf(p0, p1);
                pwv[qg][nt * 2 + 1] = (int)pack2bf(p2, p3);
            }
        }
        {
            int nkb = (kb < kb1 - 1) ? kb + 1 : kb;
#pragma unroll
            for (int nt = 0; nt < 4; nt++)
#pragma unroll
                for (int w2 = 0; w2 < 2; w2++)
                    kf[nt][w2] = *reinterpret_cast<const bf16x8*>(
                        Kp + (size_t)(nkb * 8 + nt * 2 + w2) * 512);
        }
#pragma unroll
        for (int qg = 0; qg < 2; qg++)
#pragma unroll
            for (int kc = 0; kc < 2; kc++) {
                union { int i[4]; bf16x8 v; } u;
                u.i[0] = pwv[qg][4 * kc + 0];
                u.i[1] = pwv[qg][4 * kc + 1];
                u.i[2] = pwv[qg][4 * kc + 2];
                u.i[3] = pwv[qg][4 * kc + 3];
#pragma unroll
                for (int dt = 0; dt < 4; dt++)
                    accO[dt][qg] = __builtin_amdgcn_mfma_f32_16x16x32_bf16(
                        vf[kc][dt], u.v, accO[dt][qg], 0, 0, 0);
            }
    }

    if (kvh == 1) {
#pragma unroll
        for (int dt = 0; dt < 4; dt++)
#pragma unroll
            for (int qg = 0; qg < 2; qg++)
#pragma unroll
                for (int r = 0; r < 4; r++)
                    Cmb[qpair][lane][(dt * 2 + qg) * 4 + r] = accO[dt][qg][r];
        Clsum[qpair][lane][0] = lsum[0];
        Clsum[qpair][lane][1] = lsum[1];
    }
    __syncthreads();
    if (kvh == 0) {
#pragma unroll
        for (int dt = 0; dt < 4; dt++)
#pragma unroll
            for (int qg = 0; qg < 2; qg++)
#pragma unroll
                for (int r = 0; r < 4; r++)
                    accO[dt][qg][r] += Cmb[qpair][lane][(dt * 2 + qg) * 4 + r];
        lsum[0] += Clsum[qpair][lane][0];
        lsum[1] += Clsum[qpair][lane][1];
        float inv[2];
#pragma unroll
        for (int qg = 0; qg < 2; qg++) {
            float l = lsum[qg];
            l += __shfl_xor(l, 16);
            l += __shfl_xor(l, 32);
            inv[qg] = 1.0f / l;
        }
        if constexpr (STAGE == 0) {
            u16* O = (u16*)outp;
            size_t rowb = (size_t)(b * N_ + qc * 64 + qpair * 32 + l16);
#pragma unroll
            for (int qg = 0; qg < 2; qg++)
#pragma unroll
                for (int dt = 0; dt < 4; dt++) {
                    ushort4 o;
                    o.x = f2bf(accO[dt][qg][0] * inv[qg]);
                    o.y = f2bf(accO[dt][qg][1] * inv[qg]);
                    o.z = f2bf(accO[dt][qg][2] * inv[qg]);
                    o.w = f2bf(accO[dt][qg][3] * inv[qg]);
                    *reinterpret_cast<ushort4*>(
                        &O[(rowb + qg * 16) * ostr + h * 64 + dt * 16 + g * 4]) = o;
                }
        }
    }
    if constexpr (STAGE == 1) {
        __shared__ float Os[64][68];
        if (kvh == 0) {
            float inv[2];
#pragma unroll
            for (int qg = 0; qg < 2; qg++) {
                float l = lsum[qg];
                l += __shfl_xor(l, 16);
                l += __shfl_xor(l, 32);
                inv[qg] = 1.0f / l;
            }
            int qrl = qpair * 32 + l16;
#pragma unroll
            for (int qg = 0; qg < 2; qg++)
#pragma unroll
                for (int dt = 0; dt < 4; dt++)
#pragma unroll
                    for (int r = 0; r < 4; r++)
                        Os[qrl + qg * 16][dt * 16 + g * 4 + r] = accO[dt][qg][r] * inv[qg];
        }
        __syncthreads();
        // batch-mixing scatter: n = qc*64+row; bo=(n&1)*8+h*2+(b>>3),
        // co=((n>>1)&3)*64+d, no=(b&7)*128+(n>>3); row = j*8 + (q2*2+tl)
        float* out = (float*)outp;
#pragma unroll
        for (int e = 0; e < 2; e++) {
            int seg = t + e * 256;          // 512 segs = 64 d x 8 (tl,q2)
            int d = seg & 63, tb = seg >> 6;
            int tl = tb & 1, q2 = (tb >> 1) & 3;
            int bo = tl * 8 + h * 2 + (b >> 3);
            int co = q2 * 64 + d;
            size_t base = (size_t)bo * (C_ * N_) + (size_t)co * N_ + (b & 7) * 128 + qc * 8;
            float4 v0, v1;
            v0.x = Os[0 * 8 + q2 * 2 + tl][d];
            v0.y = Os[1 * 8 + q2 * 2 + tl][d];
            v0.z = Os[2 * 8 + q2 * 2 + tl][d];
            v0.w = Os[3 * 8 + q2 * 2 + tl][d];
            v1.x = Os[4 * 8 + q2 * 2 + tl][d];
            v1.y = Os[5 * 8 + q2 * 2 + tl][d];
            v1.z = Os[6 * 8 + q2 * 2 + tl][d];
            v1.w = Os[7 * 8 + q2 * 2 + tl][d];
            *reinterpret_cast<float4*>(&out[base]) = v0;
            *reinterpret_cast<float4*>(&out[base + 4]) = v1;
        }
    }
}

extern "C" void kernel_launch(void* const* d_in, const int* in_sizes, int n_in,
                              void* d_out, int out_size, void* d_ws, size_t ws_size,
                              hipStream_t stream) {
    const float* x      = (const float*)d_in[0];
    const float* q_w    = (const float*)d_in[1];
    const float* kv_w   = (const float*)d_in[2];
    const float* proj_w = (const float*)d_in[3];
    const float* proj_b = (const float*)d_in[4];
    const float* lq_w   = (const float*)d_in[5];
    const float* lq_b   = (const float*)d_in[6];
    const float* lkv_w  = (const float*)d_in[7];
    const float* lkv_b  = (const float*)d_in[8];
    // d_in[9] = rel_bias: constant along softmax axis -> exact no-op
    const float* dw_w   = (const float*)d_in[10];
    const float* dw_b   = (const float*)d_in[11];

    const size_t SZ = (size_t)B_ * N_ * C_;  // 4M elems
    u16* ws = (u16*)d_ws;
    u16* xf    = ws;              // [0,SZ): xf, later s2in
    u16* qkv   = ws + SZ;         // [SZ,5SZ): ldc=1024: q | (unused) | q2 columns
    u16* Kpk   = ws + 5 * SZ;     // [5SZ,6SZ): packed K, also ypb between stages
    u16* Vpk   = ws + 6 * SZ;     // [6SZ,7SZ): packed V
    u16* arena = ws + 7 * SZ;     // weights: wq|wkv|wlq|wproj|wlkv
    u16* wmega  = arena;          // wq|wkv|wlq stacked: [1024][256]
    u16* wproj  = arena + 262144;
    u16* wlkv   = arena + 327680;
    float* wT   = (float*)(arena + 458752);  // [9][256] f32 transposed dw weights
    u16* yb     = qkv + 256;      // attn0 out in unused K columns (stride 1024)
    u16* ypb    = Kpk;            // proj out in dead packed-K slot
    u16* s2in   = xf;             // conv+res out in dead xf slot
    const int DIS = 1 << 30;      // pack-routing disabled sentinel

    k_prep<<<4545, 256, 0, stream>>>(q_w, kv_w, lq_w, proj_w, lkv_w, arena,
                                     dw_w, wT, x, xf);
    // mega GEMM: q (cols 0-255) | K (256-511 -> Kpk) | V (512-767 -> Vpk) |
    // q2 (768-1023, bias lq_b)
    k_gemm_bf16<<<dim3(8, 128), 256, 0, stream>>>(xf, 256, wmega, lq_b, 768,
                                                  qkv, 1024, Kpk, 256, Vpk, 512);
    k_attn_mfma<0><<<1024, 256, 0, stream>>>(qkv, 1024, Kpk, Vpk, yb, 1024);
    k_gemm_bf16<<<dim3(2, 128), 256, 0, stream>>>(yb, 1024, wproj, proj_b, 0,
                                                  ypb, 256, nullptr, DIS, nullptr, DIS);
    k_dwconv_add<<<dim3(128, B_), 256, 0, stream>>>(ypb, wT, dw_b, s2in);
    // lkv GEMM: K (cols 0-255 -> Kpk) | V (256-511 -> Vpk); bias lkv_b on all
    k_gemm_bf16<<<dim3(4, 128), 256, 0, stream>>>(s2in, 256, wlkv, lkv_b, 0,
                                                  qkv, 1024, Kpk, 0, Vpk, 256);
    k_attn_mfma<1><<<1024, 256, 0, stream>>>(qkv + 768, 1024, Kpk, Vpk, d_out, 0);
}